// Round 12
// baseline (249.393 us; speedup 1.0000x reference)
//
#include <hip/hip_runtime.h>
#include <hip/hip_bf16.h>
#include <stdint.h>

#define NROW 4096
#define FDIM 512

typedef short bf16x8 __attribute__((ext_vector_type(8)));
typedef float f32x4 __attribute__((ext_vector_type(4)));
typedef float f4 __attribute__((ext_vector_type(4)));
typedef ushort u16x4 __attribute__((ext_vector_type(4)));

#define NEG_INF (-__builtin_inff())

__device__ inline ushort f2bf(float f) {
    union { float f; uint32_t u; } c{f};
    uint32_t u = c.u;
    uint32_t r = (u + 0x7FFF + ((u >> 16) & 1)) >> 16;
    return (ushort)r;
}
__device__ inline float bf2f(ushort h) {
    union { uint32_t u; float f; } c{((uint32_t)h) << 16};
    return c.f;
}
// packed bf16 pair helpers: lo = element 0, hi = element 1
__device__ inline uint32_t cvt_pk_bf16(float lo, float hi) {
    uint32_t r;
    asm("v_cvt_pk_bf16_f32 %0, %1, %2" : "=v"(r) : "v"(lo), "v"(hi));
    return r;
}
__device__ inline float up0(uint32_t p) {
    union { uint32_t u; float f; } c{p << 16}; return c.f;
}
__device__ inline float up1(uint32_t p) {
    union { uint32_t u; float f; } c{p & 0xFFFF0000u}; return c.f;
}

__device__ inline float waveReduceMax(float v) {
    #pragma unroll
    for (int o = 32; o > 0; o >>= 1) v = fmaxf(v, __shfl_xor(v, o));
    return v;
}
__device__ inline float waveReduceSum(float v) {
    #pragma unroll
    for (int o = 32; o > 0; o >>= 1) v += __shfl_xor(v, o);
    return v;
}

// ---- sorting-network primitives (descending) -------------------------------
__device__ inline void CE(float& a, float& b) {
    float mx = fmaxf(a, b);
    b = fminf(a, b);
    a = mx;
}
// Batcher odd-even mergesort, 8 elements, descending, 19 comparators
__device__ inline void sort8(float (&l)[8]) {
    CE(l[0],l[1]); CE(l[2],l[3]); CE(l[4],l[5]); CE(l[6],l[7]);
    CE(l[0],l[2]); CE(l[1],l[3]); CE(l[4],l[6]); CE(l[5],l[7]);
    CE(l[1],l[2]); CE(l[5],l[6]);
    CE(l[0],l[4]); CE(l[1],l[5]); CE(l[2],l[6]); CE(l[3],l[7]);
    CE(l[2],l[4]); CE(l[3],l[5]);
    CE(l[1],l[2]); CE(l[3],l[4]); CE(l[5],l[6]);
}
// a, b sorted desc -> a = sorted desc top-8 of union (bitonic half-merge)
__device__ inline void mergeTop8(float (&a)[8], const float (&b)[8]) {
    float t[8];
    #pragma unroll
    for (int i = 0; i < 8; i++) t[i] = fmaxf(a[i], b[7 - i]);
    CE(t[0],t[4]); CE(t[1],t[5]); CE(t[2],t[6]); CE(t[3],t[7]);
    CE(t[0],t[2]); CE(t[1],t[3]); CE(t[4],t[6]); CE(t[5],t[7]);
    CE(t[0],t[1]); CE(t[2],t[3]); CE(t[4],t[5]); CE(t[6],t[7]);
    #pragma unroll
    for (int i = 0; i < 8; i++) a[i] = t[i];
}

#define GLL16(src, dst)                                                        \
    __builtin_amdgcn_global_load_lds(                                          \
        (const __attribute__((address_space(1))) void*)(src),                  \
        (__attribute__((address_space(3))) void*)(dst), 16, 0, 0)

// ---------------------------------------------------------------------------
__global__ __launch_bounds__(64) void coef_k(const float* __restrict__ alpha,
                                             const float* __restrict__ beta,
                                             float* __restrict__ coef) {
    if (threadIdx.x == 0) {
        float a0 = alpha[0], a1 = alpha[1], a2 = alpha[2];
        float m = fmaxf(a0, fmaxf(a1, a2));
        float e0 = expf(a0 - m), e1 = expf(a1 - m), e2 = expf(a2 - m);
        float s = e0 + e1 + e2;
        coef[0] = e0 / s; coef[1] = e1 / s; coef[2] = e2 / s;
        coef[3] = beta[0];
    }
}

// ---------------------------------------------------------------------------
// Fused preparation: all roles independent (transpose reads x directly).
__global__ __launch_bounds__(256) void prep_fused(
    const float* __restrict__ x, ushort* __restrict__ xn,
    ushort* __restrict__ xb, ushort* __restrict__ xbT,
    const float* __restrict__ W_in, ushort* __restrict__ WinT,
    const float* __restrict__ W_out, ushort* __restrict__ WoutT) {
    const int b = blockIdx.x;
    const int tid = threadIdx.x;
    __shared__ float b4[4];
    __shared__ ushort t[64][65];

    if (b < 4096) {
        const int row = b;
        int lane = tid & 63, w = tid >> 6;
        const float* xr = x + (size_t)row * FDIM;
        float v0 = xr[tid], v1 = xr[tid + 256];
        float ss = v0 * v0 + v1 * v1;
        ss = waveReduceSum(ss);
        if (lane == 0) b4[w] = ss;
        __syncthreads();
        float tot = b4[0] + b4[1] + b4[2] + b4[3];
        float inv = 1.f / fmaxf(sqrtf(tot), 1e-12f);
        size_t o = (size_t)row * FDIM + tid;
        xn[o] = f2bf(v0 * inv);  xn[o + 256] = f2bf(v1 * inv);
        xb[o] = f2bf(v0);        xb[o + 256] = f2bf(v1);
    } else if (b < 4608) {
        const int tb = b - 4096;
        const int c0 = (tb & 7) * 64, r0 = (tb >> 3) * 64;
        int lx = tid & 63, ly = tid >> 6;
        #pragma unroll
        for (int i = 0; i < 16; i++)
            t[ly + 4 * i][lx] = f2bf(x[(size_t)(r0 + ly + 4 * i) * FDIM + c0 + lx]);
        __syncthreads();
        #pragma unroll
        for (int i = 0; i < 16; i++)
            xbT[(size_t)(c0 + ly + 4 * i) * NROW + r0 + lx] = t[lx][ly + 4 * i];
    } else {
        const int cb = b - 4608;
        const float* Wf = (cb >> 6) ? W_out : W_in;
        ushort* WT = (cb >> 6) ? WoutT : WinT;
        const int idx = cb & 63;
        const int c0 = (idx & 7) * 64, r0 = (idx >> 3) * 64;
        int lx = tid & 63, ly = tid >> 6;
        #pragma unroll
        for (int i = 0; i < 16; i++)
            t[ly + 4 * i][lx] = f2bf(Wf[(size_t)(r0 + ly + 4 * i) * 512 + c0 + lx]);
        __syncthreads();
        #pragma unroll
        for (int i = 0; i < 16; i++)
            WT[(size_t)(c0 + ly + 4 * i) * 512 + r0 + lx] = t[lx][ly + 4 * i];
    }
}

// ---------------------------------------------------------------------------
// SYMMETRIC sim GEMM: simb = xn @ xn^T (bf16 out). 528 upper-triangle tiles;
// off-diagonal tiles written twice (normal + LDS-staged transposed).
__global__ __launch_bounds__(256) void gemm_sym(
    const ushort* __restrict__ A, ushort* __restrict__ C) {
    constexpr int BK = 64;
    constexpr int NT = 128 * BK;
    __shared__ __align__(16) ushort smem[128 * 130];
    ushort* As = smem;
    ushort* Bs = smem + NT;

    int bi = 0, rem = blockIdx.x;
    while (rem >= 32 - bi) { rem -= 32 - bi; bi++; }
    const int bj = bi + rem;
    const int m0 = bi * 128, n0 = bj * 128;

    const int tid = threadIdx.x;
    const int lane = tid & 63, w = tid >> 6;
    const int wr = w >> 1, wc = w & 1;

    f32x4 acc[4][4];
    #pragma unroll
    for (int mi = 0; mi < 4; mi++)
        #pragma unroll
        for (int ni = 0; ni < 4; ni++)
            #pragma unroll
            for (int r = 0; r < 4; r++) acc[mi][ni][r] = 0.f;

    for (int k0 = 0; k0 < FDIM; k0 += BK) {
        #pragma unroll
        for (int p = 0; p < 4; ++p) {
            int chunk = p * 256 + tid;
            int row = chunk / 8;
            int kc = chunk % 8;
            GLL16(A + (size_t)(m0 + row) * FDIM + k0 + kc * 8,
                  As + (size_t)(p * 256 + w * 64) * 8);
            GLL16(A + (size_t)(n0 + row) * FDIM + k0 + kc * 8,
                  Bs + (size_t)(p * 256 + w * 64) * 8);
        }
        __syncthreads();
        #pragma unroll
        for (int kf = 0; kf < BK / 32; ++kf) {
            const int ko = kf * 32 + (lane >> 4) * 8;
            bf16x8 av[4], bv[4];
            #pragma unroll
            for (int mi = 0; mi < 4; mi++)
                av[mi] = *(const bf16x8*)&As[(wr * 64 + mi * 16 + (lane & 15)) * BK + ko];
            #pragma unroll
            for (int ni = 0; ni < 4; ni++)
                bv[ni] = *(const bf16x8*)&Bs[(wc * 64 + ni * 16 + (lane & 15)) * BK + ko];
            #pragma unroll
            for (int mi = 0; mi < 4; mi++)
                #pragma unroll
                for (int ni = 0; ni < 4; ni++)
                    acc[mi][ni] = __builtin_amdgcn_mfma_f32_16x16x32_bf16(
                        av[mi], bv[ni], acc[mi][ni], 0, 0, 0);
        }
        __syncthreads();
    }

    #pragma unroll
    for (int mi = 0; mi < 4; mi++) {
        #pragma unroll
        for (int ni = 0; ni < 4; ni++) {
            int lcol = wc * 64 + ni * 16 + (lane & 15);
            #pragma unroll
            for (int r = 0; r < 4; r++) {
                int lrow = wr * 64 + mi * 16 + (lane >> 4) * 4 + r;
                ushort hv = f2bf(acc[mi][ni][r]);
                C[(size_t)(m0 + lrow) * NROW + n0 + lcol] = hv;
                smem[lrow * 130 + lcol] = hv;
            }
        }
    }

    if (bi != bj) {
        __syncthreads();
        const int wv = w;
        #pragma unroll 4
        for (int i = 0; i < 32; i++) {
            int r2 = wv * 32 + i;
            ushort a = smem[(lane * 2) * 130 + r2];
            ushort bb = smem[(lane * 2 + 1) * 130 + r2];
            uint32_t pk = (uint32_t)a | ((uint32_t)bb << 16);
            *(uint32_t*)&C[(size_t)(n0 + r2) * NROW + m0 + lane * 2] = pk;
        }
    }
}

// ---------------------------------------------------------------------------
// C = A(MxK) * B(NxK)^T, bf16 MFMA 16x16x32, 128x128 tile, 4 waves, BK=64.
// EPI 1: fp32 C + bias[col].
// EPI 3: split-K partials -> BF16. z<4: K-chunk 1024 of M@x into Pb[z];
//        z==4: H_low = xb @ WinT^T into Pb4.
template <int EPI>
__global__ __launch_bounds__(256) void gemm_abT(
    const ushort* __restrict__ A, int lda,
    const ushort* __restrict__ B, int ldb,
    int Kdim, int ldc,
    float* __restrict__ Cf, ushort* __restrict__ Pb,
    const float* __restrict__ bias,
    const ushort* __restrict__ A2, const ushort* __restrict__ B2,
    ushort* __restrict__ Pb4) {
    constexpr int BK = 64;
    constexpr int NT = 128 * BK;
    constexpr int CPR = BK / 8;
    constexpr int PASSES = (128 * CPR) / 256;
    __shared__ __align__(16) ushort smem[2 * NT];
    ushort* As = smem;
    ushort* Bs = smem + NT;

    int Kd = Kdim;
    if constexpr (EPI == 3) {
        if (blockIdx.z == 4) {
            A = A2; lda = FDIM; B = B2; ldb = FDIM; Kd = FDIM;
            Pb = Pb4;
        } else {
            A += (size_t)blockIdx.z * 1024;
            B += (size_t)blockIdx.z * 1024;
            Pb += (size_t)blockIdx.z * ((size_t)NROW * 512);
        }
    }

    const int tid = threadIdx.x;
    const int lane = tid & 63, w = tid >> 6;
    const int wr = w >> 1, wc = w & 1;
    const int m0 = blockIdx.y * 128;
    const int n0 = blockIdx.x * 128;

    f32x4 acc[4][4];
    #pragma unroll
    for (int mi = 0; mi < 4; mi++)
        #pragma unroll
        for (int ni = 0; ni < 4; ni++)
            #pragma unroll
            for (int r = 0; r < 4; r++) acc[mi][ni][r] = 0.f;

    for (int k0 = 0; k0 < Kd; k0 += BK) {
        #pragma unroll
        for (int p = 0; p < PASSES; ++p) {
            int chunk = p * 256 + tid;
            int row = chunk / CPR;
            int kc = chunk % CPR;
            const ushort* asrc = A + (size_t)(m0 + row) * lda + k0 + kc * 8;
            const ushort* bsrc = B + (size_t)(n0 + row) * ldb + k0 + kc * 8;
            ushort* abase = As + (size_t)(p * 256 + w * 64) * 8;
            ushort* bbase = Bs + (size_t)(p * 256 + w * 64) * 8;
            GLL16(asrc, abase);
            GLL16(bsrc, bbase);
        }
        __syncthreads();
        #pragma unroll
        for (int kf = 0; kf < BK / 32; ++kf) {
            const int ko = kf * 32 + (lane >> 4) * 8;
            bf16x8 av[4], bv[4];
            #pragma unroll
            for (int mi = 0; mi < 4; mi++)
                av[mi] = *(const bf16x8*)&As[(wr * 64 + mi * 16 + (lane & 15)) * BK + ko];
            #pragma unroll
            for (int ni = 0; ni < 4; ni++)
                bv[ni] = *(const bf16x8*)&Bs[(wc * 64 + ni * 16 + (lane & 15)) * BK + ko];
            #pragma unroll
            for (int mi = 0; mi < 4; mi++)
                #pragma unroll
                for (int ni = 0; ni < 4; ni++)
                    acc[mi][ni] = __builtin_amdgcn_mfma_f32_16x16x32_bf16(
                        av[mi], bv[ni], acc[mi][ni], 0, 0, 0);
        }
        __syncthreads();
    }

    #pragma unroll
    for (int mi = 0; mi < 4; mi++) {
        #pragma unroll
        for (int ni = 0; ni < 4; ni++) {
            int col = n0 + wc * 64 + ni * 16 + (lane & 15);
            #pragma unroll
            for (int r = 0; r < 4; r++) {
                int rowg = m0 + wr * 64 + mi * 16 + (lane >> 4) * 4 + r;
                size_t off = (size_t)rowg * ldc + col;
                float v = acc[mi][ni][r];
                if constexpr (EPI == 1) {
                    Cf[off] = v + bias[col];
                } else {
                    Pb[off] = f2bf(v);
                }
            }
        }
    }
}

// ---------------------------------------------------------------------------
// topk + build M — r12: ONE WAVE PER ROW, zero barriers, zero LDS, adj read
// ONCE (held packed bf16: 32 VGPR for 64 cols/lane).  macc accumulated as
// packed bf16 pairs (32 VGPR, rounding adds ~4e-3 to output vs 0.14 thr).
// Rationale: memory:compute demand is ~8:1 (416MB vs ~30us VALU), so the
// kernel must be memory-bound — but every barrier-phased structure (r3-r11,
// all 128-148us) left the memory pipe EMPTY during lockstep compute phases.
// Fully independent waves self-stagger and keep loads continuously queued.
// Per row: per hop {load rmask+adj in 4 groups (unroll 2 caps transient
// VGPR), running per-lane top-8, ONE 6-level shfl tree (1/4 the old
// redundant tree work), thr = l[7], macc += aksq*adj*mask}; write M.
// Spill tripwire: WRITE_SIZE must stay 32768 KB; VGPR target <= ~200.
__global__ __launch_bounds__(256) void topk_build_M(
    const ushort* __restrict__ simb, const float* __restrict__ adj,
    const float* __restrict__ rmask, const float* __restrict__ coef,
    ushort* __restrict__ Mout) {
    const int lane = threadIdx.x & 63;
    const int w = threadIdx.x >> 6;
    const int row = blockIdx.x * 4 + w;
    const int loff = lane * 4;
    const size_t hs = (size_t)NROW * NROW;

    const ushort* srow = simb + (size_t)row * NROW + loff;
    const float* arow = adj + (size_t)row * NROW + loff;
    const float* rrow = rmask + (size_t)row * NROW + loff;

    // sim: 64 cols/lane as 16 packed-pairs-of-pairs (uint2 = 4 bf16)
    uint2 svp[16];
    #pragma unroll
    for (int i = 0; i < 16; i++) svp[i] = *(const uint2*)(srow + i * 256);

    // macc: packed bf16 pairs, accumulated across hops
    uint32_t mp[16][2];
    #pragma unroll
    for (int i = 0; i < 16; i++) { mp[i][0] = 0u; mp[i][1] = 0u; }

    #pragma unroll 1
    for (int k = 0; k < 3; ++k) {
        const float* ar = arow + (size_t)k * hs;
        const float* rr = rrow + (size_t)k * hs;

        uint2 avp[16];
        uint32_t rb[2] = {0u, 0u};
        float run[8];

        // 4 groups of 16 cols; unroll 2 bounds transient load registers
        #pragma unroll 2
        for (int g = 0; g < 4; ++g) {
            f4 rv[4], a[4];
            #pragma unroll
            for (int i = 0; i < 4; i++)
                rv[i] = *(const f4*)(rr + (g * 4 + i) * 256);
            #pragma unroll
            for (int i = 0; i < 4; i++)
                a[i] = *(const f4*)(ar + (g * 4 + i) * 256);

            #pragma unroll
            for (int i = 0; i < 4; i++) {
                const int bit = (g * 4 + i) * 4 & 31;
                uint32_t bits = (rv[i].x < 0.5f ? 1u : 0u)
                              | (rv[i].y < 0.5f ? 2u : 0u)
                              | (rv[i].z < 0.5f ? 4u : 0u)
                              | (rv[i].w < 0.5f ? 8u : 0u);
                rb[g >> 1] |= bits << bit;
            }
            #pragma unroll
            for (int i = 0; i < 4; i++) {
                avp[g * 4 + i].x = cvt_pk_bf16(a[i].x, a[i].y);
                avp[g * 4 + i].y = cvt_pk_bf16(a[i].z, a[i].w);
            }

            // 16 rounded products -> sorted top-8 of the group
            float t[8], u[8];
            #pragma unroll
            for (int i = 0; i < 2; i++) {
                const int q = g * 4 + i;
                t[i * 4 + 0] = up0(avp[q].x) * up0(svp[q].x);
                t[i * 4 + 1] = up1(avp[q].x) * up1(svp[q].x);
                t[i * 4 + 2] = up0(avp[q].y) * up0(svp[q].y);
                t[i * 4 + 3] = up1(avp[q].y) * up1(svp[q].y);
            }
            #pragma unroll
            for (int i = 0; i < 2; i++) {
                const int q = g * 4 + 2 + i;
                u[i * 4 + 0] = up0(avp[q].x) * up0(svp[q].x);
                u[i * 4 + 1] = up1(avp[q].x) * up1(svp[q].x);
                u[i * 4 + 2] = up0(avp[q].y) * up0(svp[q].y);
                u[i * 4 + 3] = up1(avp[q].y) * up1(svp[q].y);
            }
            sort8(t);
            sort8(u);
            mergeTop8(t, u);
            if (g == 0) {
                #pragma unroll
                for (int i = 0; i < 8; i++) run[i] = t[i];
            } else {
                mergeTop8(run, t);
            }
        }

        // row-global top-8: 6-level butterfly (once per row, all lanes conv.)
        #pragma unroll
        for (int lvl = 0; lvl < 6; lvl++) {
            float b[8];
            #pragma unroll
            for (int i = 0; i < 8; i++) b[i] = __shfl_xor(run[i], 1 << lvl);
            mergeTop8(run, b);
        }
        const float thr = run[7];

        const float ak = coef[k];
        const float aksq = ak * ak;
        #pragma unroll
        for (int i = 0; i < 16; i++) {
            float a0 = up0(avp[i].x), a1 = up1(avp[i].x);
            float a2 = up0(avp[i].y), a3 = up1(avp[i].y);
            float s0 = up0(svp[i].x), s1 = up1(svp[i].x);
            float s2 = up0(svp[i].y), s3 = up1(svp[i].y);
            const uint32_t bits = rb[i >> 3] >> ((i * 4) & 31);
            bool m0 = (bits & 1) || (a0 * s0 >= thr);
            bool m1 = (bits & 2) || (a1 * s1 >= thr);
            bool m2 = (bits & 4) || (a2 * s2 >= thr);
            bool m3 = (bits & 8) || (a3 * s3 >= thr);
            float d0 = m0 ? aksq * a0 : 0.f;
            float d1 = m1 ? aksq * a1 : 0.f;
            float d2 = m2 ? aksq * a2 : 0.f;
            float d3 = m3 ? aksq * a3 : 0.f;
            mp[i][0] = cvt_pk_bf16(up0(mp[i][0]) + d0, up1(mp[i][0]) + d1);
            mp[i][1] = cvt_pk_bf16(up0(mp[i][1]) + d2, up1(mp[i][1]) + d3);
        }
    }

    ushort* mrow = Mout + (size_t)row * NROW + loff;
    #pragma unroll
    for (int i = 0; i < 16; i++) {
        u16x4 o;
        o[0] = f2bf(up0(svp[i].x) * up0(mp[i][0]));
        o[1] = f2bf(up1(svp[i].x) * up1(mp[i][0]));
        o[2] = f2bf(up0(svp[i].y) * up0(mp[i][1]));
        o[3] = f2bf(up1(svp[i].y) * up1(mp[i][1]));
        *(u16x4*)(mrow + i * 256) = o;
    }
}

// ---------------------------------------------------------------------------
// H = relu(cb*(parts4 + bias) + (1-cb)*sum_{z<4} parts[z]) -> bf16
__global__ __launch_bounds__(256) void reduce_relu(
    const ushort* __restrict__ parts, const ushort* __restrict__ parts4,
    const float* __restrict__ bias, const float* __restrict__ coef,
    ushort* __restrict__ Hb) {
    const size_t i = (size_t)blockIdx.x * 256 + threadIdx.x;  // u16x4 index
    f4 s = {0.f, 0.f, 0.f, 0.f};
    #pragma unroll
    for (int z = 0; z < 4; z++) {
        u16x4 p = *((const u16x4*)parts + (size_t)z * 524288 + i);
        #pragma unroll
        for (int c = 0; c < 4; c++) s[c] += bf2f(p[c]);
    }
    u16x4 h4 = *((const u16x4*)parts4 + i);
    f4 bi = ((const f4*)bias)[i & 127];
    float cb = coef[3];
    u16x4 o;
    #pragma unroll
    for (int c = 0; c < 4; c++) {
        float h = cb * (bf2f(h4[c]) + bi[c]) + (1.f - cb) * s[c];
        o[c] = f2bf(fmaxf(h, 0.f));
    }
    *((u16x4*)Hb + i) = o;
}

// ---------------------------------------------------------------------------
__global__ __launch_bounds__(256) void logsoftmax_k(const float* __restrict__ L,
                                                    float* __restrict__ out) {
    int row = blockIdx.x, tid = threadIdx.x;
    int lane = tid & 63, w = tid >> 6;
    const float* lr = L + (size_t)row * 512;
    float v0 = lr[tid], v1 = lr[tid + 256];
    __shared__ float bm[4], bs[4];
    float m = fmaxf(v0, v1);
    m = waveReduceMax(m);
    if (lane == 0) bm[w] = m;
    __syncthreads();
    float M = fmaxf(fmaxf(bm[0], bm[1]), fmaxf(bm[2], bm[3]));
    float s = expf(v0 - M) + expf(v1 - M);
    s = waveReduceSum(s);
    if (lane == 0) bs[w] = s;
    __syncthreads();
    float S = bs[0] + bs[1] + bs[2] + bs[3];
    float lse = M + logf(S);
    float* orow = out + (size_t)row * 512;
    orow[tid] = v0 - lse;
    orow[tid + 256] = v1 - lse;
}

// ---------------------------------------------------------------------------
extern "C" void kernel_launch(void* const* d_in, const int* in_sizes, int n_in,
                              void* d_out, int out_size, void* d_ws, size_t ws_size,
                              hipStream_t stream) {
    const float* x     = (const float*)d_in[0];
    const float* adj   = (const float*)d_in[1];
    const float* rmask = (const float*)d_in[2];
    const float* W_in  = (const float*)d_in[3];
    const float* b_in  = (const float*)d_in[4];
    const float* W_out = (const float*)d_in[5];
    const float* b_out = (const float*)d_in[6];
    const float* alpha = (const float*)d_in[7];
    const float* beta  = (const float*)d_in[8];
    float* out = (float*)d_out;

    const size_t MB = 1024 * 1024;
    char* wsb = (char*)d_ws;
    // [0,32):  simb bf16 (dead after topk) -> parts bf16 4x4MB [0,16)
    //          + parts4 bf16 [16,20) + logits fp32 [20,28)
    // [32,64): Mb bf16
    // [64,68): xn bf16    [68,72): xb bf16    [72,76): xbT bf16
    // [76,76.5): WinT     [76.5,77): WoutT
    // [85,89): Hb bf16    [89): coef
    ushort* simb   = (ushort*)wsb;
    ushort* parts  = (ushort*)wsb;
    ushort* parts4 = (ushort*)(wsb + 16 * MB);
    float*  logits = (float*)(wsb + 20 * MB);
    ushort* Mb     = (ushort*)(wsb + 32 * MB);
    ushort* xn     = (ushort*)(wsb + 64 * MB);
    ushort* xb     = (ushort*)(wsb + 68 * MB);
    ushort* xbT    = (ushort*)(wsb + 72 * MB);
    ushort* WinT   = (ushort*)(wsb + 76 * MB);
    ushort* WoutT  = (ushort*)(wsb + 76 * MB + 512 * 1024);
    ushort* Hb     = (ushort*)(wsb + 85 * MB);
    float*  coef   = (float*)(wsb + 89 * MB);

    coef_k<<<1, 64, 0, stream>>>(alpha, beta, coef);

    // fused prep: xn/xb + x^T + both weight transposes (all independent)
    prep_fused<<<4096 + 512 + 128, 256, 0, stream>>>(
        x, xn, xb, xbT, W_in, WinT, W_out, WoutT);

    // sim = xn @ xn^T -> bf16 (symmetric: 528 upper-triangle tiles)
    gemm_sym<<<528, 256, 0, stream>>>(xn, simb);

    // combined masked adjacency M (bf16) — 1 wave/row, barrier-free
    topk_build_M<<<NROW / 4, 256, 0, stream>>>(simb, adj, rmask, coef, Mb);

    // split-K M@x (z<4) + H_low (z=4) in ONE dispatch; bf16 partials
    gemm_abT<3><<<dim3(4, 32, 5), 256, 0, stream>>>(
        Mb, NROW, xbT, NROW, 1024, 512, nullptr, parts, nullptr,
        xb, WinT, parts4);

    // H = relu(b*(H_low+bias) + (1-b)*sum parts) -> bf16
    reduce_relu<<<2048, 256, 0, stream>>>(parts, parts4, b_in, coef, Hb);

    // logits = H @ W_out + b_out
    gemm_abT<1><<<dim3(4, 32), 256, 0, stream>>>(
        Hb, 512, WoutT, 512, 512, 512, logits, nullptr, b_out,
        nullptr, nullptr, nullptr);

    logsoftmax_k<<<NROW, 256, 0, stream>>>(logits, out);
}

// Round 13
// 216.345 us; speedup vs baseline: 1.1528x; 1.1528x over previous
//
#include <hip/hip_runtime.h>
#include <hip/hip_bf16.h>
#include <stdint.h>

#define NROW 4096
#define FDIM 512

typedef short bf16x8 __attribute__((ext_vector_type(8)));
typedef float f32x4 __attribute__((ext_vector_type(4)));
typedef float f4 __attribute__((ext_vector_type(4)));
typedef ushort u16x4 __attribute__((ext_vector_type(4)));

#define NEG_INF (-__builtin_inff())

__device__ inline ushort f2bf(float f) {
    union { float f; uint32_t u; } c{f};
    uint32_t u = c.u;
    uint32_t r = (u + 0x7FFF + ((u >> 16) & 1)) >> 16;
    return (ushort)r;
}
__device__ inline float bf2f(ushort h) {
    union { uint32_t u; float f; } c{((uint32_t)h) << 16};
    return c.f;
}
// packed bf16 pair helpers: lo = element 0, hi = element 1
__device__ inline uint32_t cvt_pk_bf16(float lo, float hi) {
    uint32_t r;
    asm("v_cvt_pk_bf16_f32 %0, %1, %2" : "=v"(r) : "v"(lo), "v"(hi));
    return r;
}
__device__ inline float up0(uint32_t p) {
    union { uint32_t u; float f; } c{p << 16}; return c.f;
}
__device__ inline float up1(uint32_t p) {
    union { uint32_t u; float f; } c{p & 0xFFFF0000u}; return c.f;
}

__device__ inline float waveReduceMax(float v) {
    #pragma unroll
    for (int o = 32; o > 0; o >>= 1) v = fmaxf(v, __shfl_xor(v, o));
    return v;
}
__device__ inline float waveReduceSum(float v) {
    #pragma unroll
    for (int o = 32; o > 0; o >>= 1) v += __shfl_xor(v, o);
    return v;
}

// ---- sorting-network primitives (descending) -------------------------------
__device__ inline void CE(float& a, float& b) {
    float mx = fmaxf(a, b);
    b = fminf(a, b);
    a = mx;
}
// Batcher odd-even mergesort, 8 elements, descending, 19 comparators
__device__ inline void sort8(float (&l)[8]) {
    CE(l[0],l[1]); CE(l[2],l[3]); CE(l[4],l[5]); CE(l[6],l[7]);
    CE(l[0],l[2]); CE(l[1],l[3]); CE(l[4],l[6]); CE(l[5],l[7]);
    CE(l[1],l[2]); CE(l[5],l[6]);
    CE(l[0],l[4]); CE(l[1],l[5]); CE(l[2],l[6]); CE(l[3],l[7]);
    CE(l[2],l[4]); CE(l[3],l[5]);
    CE(l[1],l[2]); CE(l[3],l[4]); CE(l[5],l[6]);
}
// a, b sorted desc -> a = sorted desc top-8 of union (bitonic half-merge)
__device__ inline void mergeTop8(float (&a)[8], const float (&b)[8]) {
    float t[8];
    #pragma unroll
    for (int i = 0; i < 8; i++) t[i] = fmaxf(a[i], b[7 - i]);
    CE(t[0],t[4]); CE(t[1],t[5]); CE(t[2],t[6]); CE(t[3],t[7]);
    CE(t[0],t[2]); CE(t[1],t[3]); CE(t[4],t[6]); CE(t[5],t[7]);
    CE(t[0],t[1]); CE(t[2],t[3]); CE(t[4],t[5]); CE(t[6],t[7]);
    #pragma unroll
    for (int i = 0; i < 8; i++) a[i] = t[i];
}
// 8th-largest of union of two sorted-8 lists: min of the bitonic half-merge
__device__ inline float merge8th(const float (&a)[8], const float (&b)[8]) {
    float t0 = fminf(fmaxf(a[0], b[7]), fmaxf(a[1], b[6]));
    float t1 = fminf(fmaxf(a[2], b[5]), fmaxf(a[3], b[4]));
    float t2 = fminf(fmaxf(a[4], b[3]), fmaxf(a[5], b[2]));
    float t3 = fminf(fmaxf(a[6], b[1]), fmaxf(a[7], b[0]));
    return fminf(fminf(t0, t1), fminf(t2, t3));
}

#define GLL16(src, dst)                                                        \
    __builtin_amdgcn_global_load_lds(                                          \
        (const __attribute__((address_space(1))) void*)(src),                  \
        (__attribute__((address_space(3))) void*)(dst), 16, 0, 0)

// ---------------------------------------------------------------------------
// Fused preparation: all roles independent (transpose reads x directly).
// blocks [0,4096):    prep_x — row normalize -> xn bf16; cast -> xb bf16
// blocks [4096,4608): transpose x (fp32) -> xbT bf16 (512x4096)
// blocks [4608,4736): conv+transpose W_in / W_out -> WinT / WoutT
// block  4736:        coef = softmax(alpha), beta
__global__ __launch_bounds__(256) void prep_fused(
    const float* __restrict__ x, ushort* __restrict__ xn,
    ushort* __restrict__ xb, ushort* __restrict__ xbT,
    const float* __restrict__ W_in, ushort* __restrict__ WinT,
    const float* __restrict__ W_out, ushort* __restrict__ WoutT,
    const float* __restrict__ alpha, const float* __restrict__ beta,
    float* __restrict__ coef) {
    const int b = blockIdx.x;
    const int tid = threadIdx.x;
    __shared__ float b4[4];
    __shared__ ushort t[64][65];

    if (b >= 4736) {
        if (tid == 0) {
            float a0 = alpha[0], a1 = alpha[1], a2 = alpha[2];
            float m = fmaxf(a0, fmaxf(a1, a2));
            float e0 = expf(a0 - m), e1 = expf(a1 - m), e2 = expf(a2 - m);
            float s = e0 + e1 + e2;
            coef[0] = e0 / s; coef[1] = e1 / s; coef[2] = e2 / s;
            coef[3] = beta[0];
        }
    } else if (b < 4096) {
        const int row = b;
        int lane = tid & 63, w = tid >> 6;
        const float* xr = x + (size_t)row * FDIM;
        float v0 = xr[tid], v1 = xr[tid + 256];
        float ss = v0 * v0 + v1 * v1;
        ss = waveReduceSum(ss);
        if (lane == 0) b4[w] = ss;
        __syncthreads();
        float tot = b4[0] + b4[1] + b4[2] + b4[3];
        float inv = 1.f / fmaxf(sqrtf(tot), 1e-12f);
        size_t o = (size_t)row * FDIM + tid;
        xn[o] = f2bf(v0 * inv);  xn[o + 256] = f2bf(v1 * inv);
        xb[o] = f2bf(v0);        xb[o + 256] = f2bf(v1);
    } else if (b < 4608) {
        const int tb = b - 4096;
        const int c0 = (tb & 7) * 64, r0 = (tb >> 3) * 64;
        int lx = tid & 63, ly = tid >> 6;
        #pragma unroll
        for (int i = 0; i < 16; i++)
            t[ly + 4 * i][lx] = f2bf(x[(size_t)(r0 + ly + 4 * i) * FDIM + c0 + lx]);
        __syncthreads();
        #pragma unroll
        for (int i = 0; i < 16; i++)
            xbT[(size_t)(c0 + ly + 4 * i) * NROW + r0 + lx] = t[lx][ly + 4 * i];
    } else {
        const int cb = b - 4608;
        const float* Wf = (cb >> 6) ? W_out : W_in;
        ushort* WT = (cb >> 6) ? WoutT : WinT;
        const int idx = cb & 63;
        const int c0 = (idx & 7) * 64, r0 = (idx >> 3) * 64;
        int lx = tid & 63, ly = tid >> 6;
        #pragma unroll
        for (int i = 0; i < 16; i++)
            t[ly + 4 * i][lx] = f2bf(Wf[(size_t)(r0 + ly + 4 * i) * 512 + c0 + lx]);
        __syncthreads();
        #pragma unroll
        for (int i = 0; i < 16; i++)
            WT[(size_t)(c0 + ly + 4 * i) * 512 + r0 + lx] = t[lx][ly + 4 * i];
    }
}

// ---------------------------------------------------------------------------
// SYMMETRIC sim GEMM: simb = xn @ xn^T (bf16 out). 528 upper-triangle tiles;
// off-diagonal tiles written twice (normal + LDS-staged transposed).
__global__ __launch_bounds__(256) void gemm_sym(
    const ushort* __restrict__ A, ushort* __restrict__ C) {
    constexpr int BK = 64;
    constexpr int NT = 128 * BK;
    __shared__ __align__(16) ushort smem[128 * 130];
    ushort* As = smem;
    ushort* Bs = smem + NT;

    int bi = 0, rem = blockIdx.x;
    while (rem >= 32 - bi) { rem -= 32 - bi; bi++; }
    const int bj = bi + rem;
    const int m0 = bi * 128, n0 = bj * 128;

    const int tid = threadIdx.x;
    const int lane = tid & 63, w = tid >> 6;
    const int wr = w >> 1, wc = w & 1;

    f32x4 acc[4][4];
    #pragma unroll
    for (int mi = 0; mi < 4; mi++)
        #pragma unroll
        for (int ni = 0; ni < 4; ni++)
            #pragma unroll
            for (int r = 0; r < 4; r++) acc[mi][ni][r] = 0.f;

    for (int k0 = 0; k0 < FDIM; k0 += BK) {
        #pragma unroll
        for (int p = 0; p < 4; ++p) {
            int chunk = p * 256 + tid;
            int row = chunk / 8;
            int kc = chunk % 8;
            GLL16(A + (size_t)(m0 + row) * FDIM + k0 + kc * 8,
                  As + (size_t)(p * 256 + w * 64) * 8);
            GLL16(A + (size_t)(n0 + row) * FDIM + k0 + kc * 8,
                  Bs + (size_t)(p * 256 + w * 64) * 8);
        }
        __syncthreads();
        #pragma unroll
        for (int kf = 0; kf < BK / 32; ++kf) {
            const int ko = kf * 32 + (lane >> 4) * 8;
            bf16x8 av[4], bv[4];
            #pragma unroll
            for (int mi = 0; mi < 4; mi++)
                av[mi] = *(const bf16x8*)&As[(wr * 64 + mi * 16 + (lane & 15)) * BK + ko];
            #pragma unroll
            for (int ni = 0; ni < 4; ni++)
                bv[ni] = *(const bf16x8*)&Bs[(wc * 64 + ni * 16 + (lane & 15)) * BK + ko];
            #pragma unroll
            for (int mi = 0; mi < 4; mi++)
                #pragma unroll
                for (int ni = 0; ni < 4; ni++)
                    acc[mi][ni] = __builtin_amdgcn_mfma_f32_16x16x32_bf16(
                        av[mi], bv[ni], acc[mi][ni], 0, 0, 0);
        }
        __syncthreads();
    }

    #pragma unroll
    for (int mi = 0; mi < 4; mi++) {
        #pragma unroll
        for (int ni = 0; ni < 4; ni++) {
            int lcol = wc * 64 + ni * 16 + (lane & 15);
            #pragma unroll
            for (int r = 0; r < 4; r++) {
                int lrow = wr * 64 + mi * 16 + (lane >> 4) * 4 + r;
                ushort hv = f2bf(acc[mi][ni][r]);
                C[(size_t)(m0 + lrow) * NROW + n0 + lcol] = hv;
                smem[lrow * 130 + lcol] = hv;
            }
        }
    }

    if (bi != bj) {
        __syncthreads();
        const int wv = w;
        #pragma unroll 4
        for (int i = 0; i < 32; i++) {
            int r2 = wv * 32 + i;
            ushort a = smem[(lane * 2) * 130 + r2];
            ushort bb = smem[(lane * 2 + 1) * 130 + r2];
            uint32_t pk = (uint32_t)a | ((uint32_t)bb << 16);
            *(uint32_t*)&C[(size_t)(n0 + r2) * NROW + m0 + lane * 2] = pk;
        }
    }
}

// ---------------------------------------------------------------------------
// C = A(MxK) * B(NxK)^T, bf16 MFMA 16x16x32, 128x128 tile, 4 waves, BK=64.
// EPI 1: fp32 C + bias[col].
// EPI 3: split-K partials -> BF16. z<8: K-chunk 512 of M@x into Pb[z];
//        z==8: H_low = xb @ WinT^T into Pb4.
template <int EPI>
__global__ __launch_bounds__(256) void gemm_abT(
    const ushort* __restrict__ A, int lda,
    const ushort* __restrict__ B, int ldb,
    int Kdim, int ldc,
    float* __restrict__ Cf, ushort* __restrict__ Pb,
    const float* __restrict__ bias,
    const ushort* __restrict__ A2, const ushort* __restrict__ B2,
    ushort* __restrict__ Pb4) {
    constexpr int BK = 64;
    constexpr int NT = 128 * BK;
    constexpr int CPR = BK / 8;
    constexpr int PASSES = (128 * CPR) / 256;
    __shared__ __align__(16) ushort smem[2 * NT];
    ushort* As = smem;
    ushort* Bs = smem + NT;

    int Kd = Kdim;
    if constexpr (EPI == 3) {
        if (blockIdx.z == 8) {
            A = A2; lda = FDIM; B = B2; ldb = FDIM; Kd = FDIM;
            Pb = Pb4;
        } else {
            A += (size_t)blockIdx.z * 512;
            B += (size_t)blockIdx.z * 512;
            Pb += (size_t)blockIdx.z * ((size_t)NROW * 512);
        }
    }

    const int tid = threadIdx.x;
    const int lane = tid & 63, w = tid >> 6;
    const int wr = w >> 1, wc = w & 1;
    const int m0 = blockIdx.y * 128;
    const int n0 = blockIdx.x * 128;

    f32x4 acc[4][4];
    #pragma unroll
    for (int mi = 0; mi < 4; mi++)
        #pragma unroll
        for (int ni = 0; ni < 4; ni++)
            #pragma unroll
            for (int r = 0; r < 4; r++) acc[mi][ni][r] = 0.f;

    for (int k0 = 0; k0 < Kd; k0 += BK) {
        #pragma unroll
        for (int p = 0; p < PASSES; ++p) {
            int chunk = p * 256 + tid;
            int row = chunk / CPR;
            int kc = chunk % CPR;
            const ushort* asrc = A + (size_t)(m0 + row) * lda + k0 + kc * 8;
            const ushort* bsrc = B + (size_t)(n0 + row) * ldb + k0 + kc * 8;
            ushort* abase = As + (size_t)(p * 256 + w * 64) * 8;
            ushort* bbase = Bs + (size_t)(p * 256 + w * 64) * 8;
            GLL16(asrc, abase);
            GLL16(bsrc, bbase);
        }
        __syncthreads();
        #pragma unroll
        for (int kf = 0; kf < BK / 32; ++kf) {
            const int ko = kf * 32 + (lane >> 4) * 8;
            bf16x8 av[4], bv[4];
            #pragma unroll
            for (int mi = 0; mi < 4; mi++)
                av[mi] = *(const bf16x8*)&As[(wr * 64 + mi * 16 + (lane & 15)) * BK + ko];
            #pragma unroll
            for (int ni = 0; ni < 4; ni++)
                bv[ni] = *(const bf16x8*)&Bs[(wc * 64 + ni * 16 + (lane & 15)) * BK + ko];
            #pragma unroll
            for (int mi = 0; mi < 4; mi++)
                #pragma unroll
                for (int ni = 0; ni < 4; ni++)
                    acc[mi][ni] = __builtin_amdgcn_mfma_f32_16x16x32_bf16(
                        av[mi], bv[ni], acc[mi][ni], 0, 0, 0);
        }
        __syncthreads();
    }

    #pragma unroll
    for (int mi = 0; mi < 4; mi++) {
        #pragma unroll
        for (int ni = 0; ni < 4; ni++) {
            int col = n0 + wc * 64 + ni * 16 + (lane & 15);
            #pragma unroll
            for (int r = 0; r < 4; r++) {
                int rowg = m0 + wr * 64 + mi * 16 + (lane >> 4) * 4 + r;
                size_t off = (size_t)rowg * ldc + col;
                float v = acc[mi][ni][r];
                if constexpr (EPI == 1) {
                    Cf[off] = v + bias[col];
                } else {
                    Pb[off] = f2bf(v);
                }
            }
        }
    }
}

// ---------------------------------------------------------------------------
// topk + build M — r11 structure verbatim (best measured: 133us, VGPR 64,
// no spill): 512-thread blocks = 8 waves = 2 independent rows, 4 waves/row,
// lane owns 16 cols, one barrier per hop (3 total).
// r13 adds s_setprio(1) around the sort/tree VALU section (T5 — helps when
// resident waves are at different phases; topk's self-staggered blocks have
// partial diversity; ~0 cost if null).
// r12 lesson (WRITE_SIZE 163MB): >~64 persistent VGPRs spill; r11's 64 fits.
// Spill tripwire: WRITE_SIZE must stay 32768 KB.
__global__ __launch_bounds__(512) void topk_build_M(
    const ushort* __restrict__ simb, const float* __restrict__ adj,
    const float* __restrict__ rmask, const float* __restrict__ coef,
    ushort* __restrict__ Mout) {
    const int tid = threadIdx.x;
    const int lane = tid & 63;
    const int w = tid >> 6;
    const int rloc = w >> 2;
    const int wv = w & 3;
    const int row = blockIdx.x * 2 + rloc;
    __shared__ float wl[2][3][4][8];

    const int cbase = wv * 1024 + lane * 4;
    const size_t hopstride = (size_t)NROW * NROW;

    const ushort* srow = simb + (size_t)row * NROW + cbase;
    const float* arow = adj + (size_t)row * NROW + cbase;
    const float* rrow = rmask + (size_t)row * NROW + cbase;

    uint2 svp[4];
    #pragma unroll
    for (int q = 0; q < 4; q++)
        svp[q] = *(const uint2*)(srow + q * 256);

    float macc[4][4];
    #pragma unroll
    for (int q = 0; q < 4; q++)
        #pragma unroll
        for (int c = 0; c < 4; c++) macc[q][c] = 0.f;

    #pragma unroll 1
    for (int k = 0; k < 3; ++k) {
        const float* ar = arow + (size_t)k * hopstride;
        const float* rr = rrow + (size_t)k * hopstride;

        f4 rv[4], a[4];
        #pragma unroll
        for (int q = 0; q < 4; q++) rv[q] = *(const f4*)(rr + q * 256);
        #pragma unroll
        for (int q = 0; q < 4; q++) a[q] = *(const f4*)(ar + q * 256);

        uint32_t rbits = 0;
        #pragma unroll
        for (int q = 0; q < 4; q++) {
            rbits |= (rv[q].x < 0.5f ? 1u : 0u) << (q * 4 + 0);
            rbits |= (rv[q].y < 0.5f ? 1u : 0u) << (q * 4 + 1);
            rbits |= (rv[q].z < 0.5f ? 1u : 0u) << (q * 4 + 2);
            rbits |= (rv[q].w < 0.5f ? 1u : 0u) << (q * 4 + 3);
        }

        uint2 avp[4];
        #pragma unroll
        for (int q = 0; q < 4; q++) {
            avp[q].x = cvt_pk_bf16(a[q].x, a[q].y);
            avp[q].y = cvt_pk_bf16(a[q].z, a[q].w);
        }

        __builtin_amdgcn_s_setprio(1);
        float lo8[8], hi8[8];
        #pragma unroll
        for (int qq = 0; qq < 2; qq++) {
            lo8[qq * 4 + 0] = up0(avp[qq].x) * up0(svp[qq].x);
            lo8[qq * 4 + 1] = up1(avp[qq].x) * up1(svp[qq].x);
            lo8[qq * 4 + 2] = up0(avp[qq].y) * up0(svp[qq].y);
            lo8[qq * 4 + 3] = up1(avp[qq].y) * up1(svp[qq].y);
        }
        #pragma unroll
        for (int qq = 0; qq < 2; qq++) {
            const int q = 2 + qq;
            hi8[qq * 4 + 0] = up0(avp[q].x) * up0(svp[q].x);
            hi8[qq * 4 + 1] = up1(avp[q].x) * up1(svp[q].x);
            hi8[qq * 4 + 2] = up0(avp[q].y) * up0(svp[q].y);
            hi8[qq * 4 + 3] = up1(avp[q].y) * up1(svp[q].y);
        }
        sort8(lo8);
        sort8(hi8);
        mergeTop8(lo8, hi8);

        // wave top-8: 6-level merge tree
        #pragma unroll
        for (int lvl = 0; lvl < 6; lvl++) {
            float b[8];
            #pragma unroll
            for (int i = 0; i < 8; i++) b[i] = __shfl_xor(lo8[i], 1 << lvl);
            mergeTop8(lo8, b);
        }
        __builtin_amdgcn_s_setprio(0);

        if (lane < 8) wl[rloc][k][wv][lane] = lo8[lane];
        __syncthreads();
        float b0[8], b1[8], b2[8];
        const int o0 = (wv + 1) & 3, o1 = (wv + 2) & 3, o2 = (wv + 3) & 3;
        #pragma unroll
        for (int i = 0; i < 8; i++) b0[i] = wl[rloc][k][o0][i];
        #pragma unroll
        for (int i = 0; i < 8; i++) b1[i] = wl[rloc][k][o1][i];
        #pragma unroll
        for (int i = 0; i < 8; i++) b2[i] = wl[rloc][k][o2][i];
        mergeTop8(lo8, b0);
        mergeTop8(lo8, b1);
        const float thr = merge8th(lo8, b2);

        const float ak = coef[k];
        const float aksq = ak * ak;
        #pragma unroll
        for (int q = 0; q < 4; q++) {
            float av0 = up0(avp[q].x), av1 = up1(avp[q].x);
            float av2 = up0(avp[q].y), av3 = up1(avp[q].y);
            float s0 = up0(svp[q].x), s1 = up1(svp[q].x);
            float s2 = up0(svp[q].y), s3 = up1(svp[q].y);
            bool m0 = ((rbits >> (q * 4 + 0)) & 1) || (av0 * s0 >= thr);
            bool m1 = ((rbits >> (q * 4 + 1)) & 1) || (av1 * s1 >= thr);
            bool m2 = ((rbits >> (q * 4 + 2)) & 1) || (av2 * s2 >= thr);
            bool m3 = ((rbits >> (q * 4 + 3)) & 1) || (av3 * s3 >= thr);
            macc[q][0] += m0 ? aksq * av0 : 0.f;
            macc[q][1] += m1 ? aksq * av1 : 0.f;
            macc[q][2] += m2 ? aksq * av2 : 0.f;
            macc[q][3] += m3 ? aksq * av3 : 0.f;
        }
        // no end-of-loop barrier — wl[.][k+1][.] never aliases wl[.][k][.]
    }

    ushort* mrow = Mout + (size_t)row * NROW + cbase;
    #pragma unroll
    for (int q = 0; q < 4; q++) {
        u16x4 o;
        o[0] = f2bf(up0(svp[q].x) * macc[q][0]);
        o[1] = f2bf(up1(svp[q].x) * macc[q][1]);
        o[2] = f2bf(up0(svp[q].y) * macc[q][2]);
        o[3] = f2bf(up1(svp[q].y) * macc[q][3]);
        *(u16x4*)(mrow + q * 256) = o;
    }
}

// ---------------------------------------------------------------------------
// H = relu(cb*(parts8 + bias) + (1-cb)*sum_{z<8} parts[z]) -> bf16
__global__ __launch_bounds__(256) void reduce_relu(
    const ushort* __restrict__ parts, const ushort* __restrict__ parts8,
    const float* __restrict__ bias, const float* __restrict__ coef,
    ushort* __restrict__ Hb) {
    const size_t i = (size_t)blockIdx.x * 256 + threadIdx.x;  // u16x4 index
    f4 s = {0.f, 0.f, 0.f, 0.f};
    #pragma unroll
    for (int z = 0; z < 8; z++) {
        u16x4 p = *((const u16x4*)parts + (size_t)z * 524288 + i);
        #pragma unroll
        for (int c = 0; c < 4; c++) s[c] += bf2f(p[c]);
    }
    u16x4 h4 = *((const u16x4*)parts8 + i);
    f4 bi = ((const f4*)bias)[i & 127];
    float cb = coef[3];
    u16x4 o;
    #pragma unroll
    for (int c = 0; c < 4; c++) {
        float h = cb * (bf2f(h4[c]) + bi[c]) + (1.f - cb) * s[c];
        o[c] = f2bf(fmaxf(h, 0.f));
    }
    *((u16x4*)Hb + i) = o;
}

// ---------------------------------------------------------------------------
__global__ __launch_bounds__(256) void logsoftmax_k(const float* __restrict__ L,
                                                    float* __restrict__ out) {
    int row = blockIdx.x, tid = threadIdx.x;
    int lane = tid & 63, w = tid >> 6;
    const float* lr = L + (size_t)row * 512;
    float v0 = lr[tid], v1 = lr[tid + 256];
    __shared__ float bm[4], bs[4];
    float m = fmaxf(v0, v1);
    m = waveReduceMax(m);
    if (lane == 0) bm[w] = m;
    __syncthreads();
    float M = fmaxf(fmaxf(bm[0], bm[1]), fmaxf(bm[2], bm[3]));
    float s = expf(v0 - M) + expf(v1 - M);
    s = waveReduceSum(s);
    if (lane == 0) bs[w] = s;
    __syncthreads();
    float S = bs[0] + bs[1] + bs[2] + bs[3];
    float lse = M + logf(S);
    float* orow = out + (size_t)row * 512;
    orow[tid] = v0 - lse;
    orow[tid + 256] = v1 - lse;
}

// ---------------------------------------------------------------------------
extern "C" void kernel_launch(void* const* d_in, const int* in_sizes, int n_in,
                              void* d_out, int out_size, void* d_ws, size_t ws_size,
                              hipStream_t stream) {
    const float* x     = (const float*)d_in[0];
    const float* adj   = (const float*)d_in[1];
    const float* rmask = (const float*)d_in[2];
    const float* W_in  = (const float*)d_in[3];
    const float* b_in  = (const float*)d_in[4];
    const float* W_out = (const float*)d_in[5];
    const float* b_out = (const float*)d_in[6];
    const float* alpha = (const float*)d_in[7];
    const float* beta  = (const float*)d_in[8];
    float* out = (float*)d_out;

    const size_t MB = 1024 * 1024;
    char* wsb = (char*)d_ws;
    // [0,32):  simb bf16 (dead after topk) -> parts bf16 8x4MB [0,32)
    // [32,64): Mb bf16 (dead after split-K) -> logits fp32 [32,40)
    // [64,68): xn bf16    [68,72): xb bf16    [72,76): xbT bf16
    // [76,76.5): WinT     [76.5,77): WoutT
    // [77,81): parts8 (H_low partial, bf16)
    // [85,89): Hb bf16    [89): coef
    ushort* simb   = (ushort*)wsb;
    ushort* parts  = (ushort*)wsb;
    ushort* Mb     = (ushort*)(wsb + 32 * MB);
    float*  logits = (float*)(wsb + 32 * MB);
    ushort* xn     = (ushort*)(wsb + 64 * MB);
    ushort* xb     = (ushort*)(wsb + 68 * MB);
    ushort* xbT    = (ushort*)(wsb + 72 * MB);
    ushort* WinT   = (ushort*)(wsb + 76 * MB);
    ushort* WoutT  = (ushort*)(wsb + 76 * MB + 512 * 1024);
    ushort* parts8 = (ushort*)(wsb + 77 * MB);
    ushort* Hb     = (ushort*)(wsb + 85 * MB);
    float*  coef   = (float*)(wsb + 89 * MB);

    // fused prep: xn/xb + x^T + weight transposes + coef (all independent)
    prep_fused<<<4096 + 512 + 128 + 1, 256, 0, stream>>>(
        x, xn, xb, xbT, W_in, WinT, W_out, WoutT, alpha, beta, coef);

    // sim = xn @ xn^T -> bf16 (symmetric: 528 upper-triangle tiles)
    gemm_sym<<<528, 256, 0, stream>>>(xn, simb);

    // combined masked adjacency M (bf16) — 512-thread blocks, 2 rows each
    topk_build_M<<<NROW / 2, 512, 0, stream>>>(simb, adj, rmask, coef, Mb);

    // split-K=8 M@x (z<8, K=512 each) + H_low (z=8) in ONE dispatch
    gemm_abT<3><<<dim3(4, 32, 9), 256, 0, stream>>>(
        Mb, NROW, xbT, NROW, 512, 512, nullptr, parts, nullptr,
        xb, WinT, parts8);

    // H = relu(b*(H_low+bias) + (1-b)*sum parts) -> bf16
    reduce_relu<<<2048, 256, 0, stream>>>(parts, parts8, b_in, coef, Hb);

    // logits = H @ W_out + b_out  (into dead Mb region)
    gemm_abT<1><<<dim3(4, 32), 256, 0, stream>>>(
        Hb, 512, WoutT, 512, 512, 512, logits, nullptr, b_out,
        nullptr, nullptr, nullptr);

    logsoftmax_k<<<NROW, 256, 0, stream>>>(logits, out);
}

// Round 14
// 201.171 us; speedup vs baseline: 1.2397x; 1.0754x over previous
//
#include <hip/hip_runtime.h>
#include <hip/hip_bf16.h>
#include <stdint.h>

#define NROW 4096
#define FDIM 512

typedef short bf16x8 __attribute__((ext_vector_type(8)));
typedef float f32x4 __attribute__((ext_vector_type(4)));
typedef float f4 __attribute__((ext_vector_type(4)));
typedef ushort u16x4 __attribute__((ext_vector_type(4)));

#define NEG_INF (-__builtin_inff())

__device__ inline ushort f2bf(float f) {
    union { float f; uint32_t u; } c{f};
    uint32_t u = c.u;
    uint32_t r = (u + 0x7FFF + ((u >> 16) & 1)) >> 16;
    return (ushort)r;
}
__device__ inline float bf2f(ushort h) {
    union { uint32_t u; float f; } c{((uint32_t)h) << 16};
    return c.f;
}
// packed bf16 pair helpers: lo = element 0, hi = element 1
__device__ inline uint32_t cvt_pk_bf16(float lo, float hi) {
    uint32_t r;
    asm("v_cvt_pk_bf16_f32 %0, %1, %2" : "=v"(r) : "v"(lo), "v"(hi));
    return r;
}
__device__ inline float up0(uint32_t p) {
    union { uint32_t u; float f; } c{p << 16}; return c.f;
}
__device__ inline float up1(uint32_t p) {
    union { uint32_t u; float f; } c{p & 0xFFFF0000u}; return c.f;
}

__device__ inline float waveReduceMax(float v) {
    #pragma unroll
    for (int o = 32; o > 0; o >>= 1) v = fmaxf(v, __shfl_xor(v, o));
    return v;
}
__device__ inline float waveReduceSum(float v) {
    #pragma unroll
    for (int o = 32; o > 0; o >>= 1) v += __shfl_xor(v, o);
    return v;
}

// ---- sorting-network primitives (descending) -------------------------------
__device__ inline void CE(float& a, float& b) {
    float mx = fmaxf(a, b);
    b = fminf(a, b);
    a = mx;
}
// Batcher odd-even mergesort, 8 elements, descending, 19 comparators
__device__ inline void sort8(float (&l)[8]) {
    CE(l[0],l[1]); CE(l[2],l[3]); CE(l[4],l[5]); CE(l[6],l[7]);
    CE(l[0],l[2]); CE(l[1],l[3]); CE(l[4],l[6]); CE(l[5],l[7]);
    CE(l[1],l[2]); CE(l[5],l[6]);
    CE(l[0],l[4]); CE(l[1],l[5]); CE(l[2],l[6]); CE(l[3],l[7]);
    CE(l[2],l[4]); CE(l[3],l[5]);
    CE(l[1],l[2]); CE(l[3],l[4]); CE(l[5],l[6]);
}
// a, b sorted desc -> a = sorted desc top-8 of union (bitonic half-merge)
__device__ inline void mergeTop8(float (&a)[8], const float (&b)[8]) {
    float t[8];
    #pragma unroll
    for (int i = 0; i < 8; i++) t[i] = fmaxf(a[i], b[7 - i]);
    CE(t[0],t[4]); CE(t[1],t[5]); CE(t[2],t[6]); CE(t[3],t[7]);
    CE(t[0],t[2]); CE(t[1],t[3]); CE(t[4],t[6]); CE(t[5],t[7]);
    CE(t[0],t[1]); CE(t[2],t[3]); CE(t[4],t[5]); CE(t[6],t[7]);
    #pragma unroll
    for (int i = 0; i < 8; i++) a[i] = t[i];
}
// 8th-largest of union of two sorted-8 lists: min of the bitonic half-merge
__device__ inline float merge8th(const float (&a)[8], const float (&b)[8]) {
    float t0 = fminf(fmaxf(a[0], b[7]), fmaxf(a[1], b[6]));
    float t1 = fminf(fmaxf(a[2], b[5]), fmaxf(a[3], b[4]));
    float t2 = fminf(fmaxf(a[4], b[3]), fmaxf(a[5], b[2]));
    float t3 = fminf(fmaxf(a[6], b[1]), fmaxf(a[7], b[0]));
    return fminf(fminf(t0, t1), fminf(t2, t3));
}

#define GLL16(src, dst)                                                        \
    __builtin_amdgcn_global_load_lds(                                          \
        (const __attribute__((address_space(1))) void*)(src),                  \
        (__attribute__((address_space(3))) void*)(dst), 16, 0, 0)

// ---------------------------------------------------------------------------
// Fused preparation: all roles independent (transpose reads x directly).
// blocks [0,4096):    prep_x — row normalize -> xn bf16; cast -> xb bf16
// blocks [4096,4608): transpose x (fp32) -> xbT bf16 (512x4096)
// blocks [4608,4736): conv+transpose W_in / W_out -> WinT / WoutT
// block  4736:        coef = softmax(alpha), beta
__global__ __launch_bounds__(256) void prep_fused(
    const float* __restrict__ x, ushort* __restrict__ xn,
    ushort* __restrict__ xb, ushort* __restrict__ xbT,
    const float* __restrict__ W_in, ushort* __restrict__ WinT,
    const float* __restrict__ W_out, ushort* __restrict__ WoutT,
    const float* __restrict__ alpha, const float* __restrict__ beta,
    float* __restrict__ coef) {
    const int b = blockIdx.x;
    const int tid = threadIdx.x;
    __shared__ float b4[4];
    __shared__ ushort t[64][65];

    if (b >= 4736) {
        if (tid == 0) {
            float a0 = alpha[0], a1 = alpha[1], a2 = alpha[2];
            float m = fmaxf(a0, fmaxf(a1, a2));
            float e0 = expf(a0 - m), e1 = expf(a1 - m), e2 = expf(a2 - m);
            float s = e0 + e1 + e2;
            coef[0] = e0 / s; coef[1] = e1 / s; coef[2] = e2 / s;
            coef[3] = beta[0];
        }
    } else if (b < 4096) {
        const int row = b;
        int lane = tid & 63, w = tid >> 6;
        const float* xr = x + (size_t)row * FDIM;
        float v0 = xr[tid], v1 = xr[tid + 256];
        float ss = v0 * v0 + v1 * v1;
        ss = waveReduceSum(ss);
        if (lane == 0) b4[w] = ss;
        __syncthreads();
        float tot = b4[0] + b4[1] + b4[2] + b4[3];
        float inv = 1.f / fmaxf(sqrtf(tot), 1e-12f);
        size_t o = (size_t)row * FDIM + tid;
        xn[o] = f2bf(v0 * inv);  xn[o + 256] = f2bf(v1 * inv);
        xb[o] = f2bf(v0);        xb[o + 256] = f2bf(v1);
    } else if (b < 4608) {
        const int tb = b - 4096;
        const int c0 = (tb & 7) * 64, r0 = (tb >> 3) * 64;
        int lx = tid & 63, ly = tid >> 6;
        #pragma unroll
        for (int i = 0; i < 16; i++)
            t[ly + 4 * i][lx] = f2bf(x[(size_t)(r0 + ly + 4 * i) * FDIM + c0 + lx]);
        __syncthreads();
        #pragma unroll
        for (int i = 0; i < 16; i++)
            xbT[(size_t)(c0 + ly + 4 * i) * NROW + r0 + lx] = t[lx][ly + 4 * i];
    } else {
        const int cb = b - 4608;
        const float* Wf = (cb >> 6) ? W_out : W_in;
        ushort* WT = (cb >> 6) ? WoutT : WinT;
        const int idx = cb & 63;
        const int c0 = (idx & 7) * 64, r0 = (idx >> 3) * 64;
        int lx = tid & 63, ly = tid >> 6;
        #pragma unroll
        for (int i = 0; i < 16; i++)
            t[ly + 4 * i][lx] = f2bf(Wf[(size_t)(r0 + ly + 4 * i) * 512 + c0 + lx]);
        __syncthreads();
        #pragma unroll
        for (int i = 0; i < 16; i++)
            WT[(size_t)(c0 + ly + 4 * i) * 512 + r0 + lx] = t[lx][ly + 4 * i];
    }
}

// ---------------------------------------------------------------------------
// SYMMETRIC sim GEMM: simb = xn @ xn^T (bf16 out). 528 upper-triangle tiles;
// off-diagonal tiles written twice (normal + LDS-staged transposed).
__global__ __launch_bounds__(256) void gemm_sym(
    const ushort* __restrict__ A, ushort* __restrict__ C) {
    constexpr int BK = 64;
    constexpr int NT = 128 * BK;
    __shared__ __align__(16) ushort smem[128 * 130];
    ushort* As = smem;
    ushort* Bs = smem + NT;

    int bi = 0, rem = blockIdx.x;
    while (rem >= 32 - bi) { rem -= 32 - bi; bi++; }
    const int bj = bi + rem;
    const int m0 = bi * 128, n0 = bj * 128;

    const int tid = threadIdx.x;
    const int lane = tid & 63, w = tid >> 6;
    const int wr = w >> 1, wc = w & 1;

    f32x4 acc[4][4];
    #pragma unroll
    for (int mi = 0; mi < 4; mi++)
        #pragma unroll
        for (int ni = 0; ni < 4; ni++)
            #pragma unroll
            for (int r = 0; r < 4; r++) acc[mi][ni][r] = 0.f;

    for (int k0 = 0; k0 < FDIM; k0 += BK) {
        #pragma unroll
        for (int p = 0; p < 4; ++p) {
            int chunk = p * 256 + tid;
            int row = chunk / 8;
            int kc = chunk % 8;
            GLL16(A + (size_t)(m0 + row) * FDIM + k0 + kc * 8,
                  As + (size_t)(p * 256 + w * 64) * 8);
            GLL16(A + (size_t)(n0 + row) * FDIM + k0 + kc * 8,
                  Bs + (size_t)(p * 256 + w * 64) * 8);
        }
        __syncthreads();
        #pragma unroll
        for (int kf = 0; kf < BK / 32; ++kf) {
            const int ko = kf * 32 + (lane >> 4) * 8;
            bf16x8 av[4], bv[4];
            #pragma unroll
            for (int mi = 0; mi < 4; mi++)
                av[mi] = *(const bf16x8*)&As[(wr * 64 + mi * 16 + (lane & 15)) * BK + ko];
            #pragma unroll
            for (int ni = 0; ni < 4; ni++)
                bv[ni] = *(const bf16x8*)&Bs[(wc * 64 + ni * 16 + (lane & 15)) * BK + ko];
            #pragma unroll
            for (int mi = 0; mi < 4; mi++)
                #pragma unroll
                for (int ni = 0; ni < 4; ni++)
                    acc[mi][ni] = __builtin_amdgcn_mfma_f32_16x16x32_bf16(
                        av[mi], bv[ni], acc[mi][ni], 0, 0, 0);
        }
        __syncthreads();
    }

    #pragma unroll
    for (int mi = 0; mi < 4; mi++) {
        #pragma unroll
        for (int ni = 0; ni < 4; ni++) {
            int lcol = wc * 64 + ni * 16 + (lane & 15);
            #pragma unroll
            for (int r = 0; r < 4; r++) {
                int lrow = wr * 64 + mi * 16 + (lane >> 4) * 4 + r;
                ushort hv = f2bf(acc[mi][ni][r]);
                C[(size_t)(m0 + lrow) * NROW + n0 + lcol] = hv;
                smem[lrow * 130 + lcol] = hv;
            }
        }
    }

    if (bi != bj) {
        __syncthreads();
        const int wv = w;
        #pragma unroll 4
        for (int i = 0; i < 32; i++) {
            int r2 = wv * 32 + i;
            ushort a = smem[(lane * 2) * 130 + r2];
            ushort bb = smem[(lane * 2 + 1) * 130 + r2];
            uint32_t pk = (uint32_t)a | ((uint32_t)bb << 16);
            *(uint32_t*)&C[(size_t)(n0 + r2) * NROW + m0 + lane * 2] = pk;
        }
    }
}

// ---------------------------------------------------------------------------
// C = A(MxK) * B(NxK)^T, bf16 MFMA 16x16x32, 128x128 tile, 4 waves, BK=64.
// EPI 1: fp32 C + bias[col].
// EPI 3: split-K partials -> BF16. z<4: K-chunk 1024 of M@x into Pb[z];
//        z==4: H_low = xb @ WinT^T into Pb4.
template <int EPI>
__global__ __launch_bounds__(256) void gemm_abT(
    const ushort* __restrict__ A, int lda,
    const ushort* __restrict__ B, int ldb,
    int Kdim, int ldc,
    float* __restrict__ Cf, ushort* __restrict__ Pb,
    const float* __restrict__ bias,
    const ushort* __restrict__ A2, const ushort* __restrict__ B2,
    ushort* __restrict__ Pb4) {
    constexpr int BK = 64;
    constexpr int NT = 128 * BK;
    constexpr int CPR = BK / 8;
    constexpr int PASSES = (128 * CPR) / 256;
    __shared__ __align__(16) ushort smem[2 * NT];
    ushort* As = smem;
    ushort* Bs = smem + NT;

    int Kd = Kdim;
    if constexpr (EPI == 3) {
        if (blockIdx.z == 4) {
            A = A2; lda = FDIM; B = B2; ldb = FDIM; Kd = FDIM;
            Pb = Pb4;
        } else {
            A += (size_t)blockIdx.z * 1024;
            B += (size_t)blockIdx.z * 1024;
            Pb += (size_t)blockIdx.z * ((size_t)NROW * 512);
        }
    }

    const int tid = threadIdx.x;
    const int lane = tid & 63, w = tid >> 6;
    const int wr = w >> 1, wc = w & 1;
    const int m0 = blockIdx.y * 128;
    const int n0 = blockIdx.x * 128;

    f32x4 acc[4][4];
    #pragma unroll
    for (int mi = 0; mi < 4; mi++)
        #pragma unroll
        for (int ni = 0; ni < 4; ni++)
            #pragma unroll
            for (int r = 0; r < 4; r++) acc[mi][ni][r] = 0.f;

    for (int k0 = 0; k0 < Kd; k0 += BK) {
        #pragma unroll
        for (int p = 0; p < PASSES; ++p) {
            int chunk = p * 256 + tid;
            int row = chunk / CPR;
            int kc = chunk % CPR;
            const ushort* asrc = A + (size_t)(m0 + row) * lda + k0 + kc * 8;
            const ushort* bsrc = B + (size_t)(n0 + row) * ldb + k0 + kc * 8;
            ushort* abase = As + (size_t)(p * 256 + w * 64) * 8;
            ushort* bbase = Bs + (size_t)(p * 256 + w * 64) * 8;
            GLL16(asrc, abase);
            GLL16(bsrc, bbase);
        }
        __syncthreads();
        #pragma unroll
        for (int kf = 0; kf < BK / 32; ++kf) {
            const int ko = kf * 32 + (lane >> 4) * 8;
            bf16x8 av[4], bv[4];
            #pragma unroll
            for (int mi = 0; mi < 4; mi++)
                av[mi] = *(const bf16x8*)&As[(wr * 64 + mi * 16 + (lane & 15)) * BK + ko];
            #pragma unroll
            for (int ni = 0; ni < 4; ni++)
                bv[ni] = *(const bf16x8*)&Bs[(wc * 64 + ni * 16 + (lane & 15)) * BK + ko];
            #pragma unroll
            for (int mi = 0; mi < 4; mi++)
                #pragma unroll
                for (int ni = 0; ni < 4; ni++)
                    acc[mi][ni] = __builtin_amdgcn_mfma_f32_16x16x32_bf16(
                        av[mi], bv[ni], acc[mi][ni], 0, 0, 0);
        }
        __syncthreads();
    }

    #pragma unroll
    for (int mi = 0; mi < 4; mi++) {
        #pragma unroll
        for (int ni = 0; ni < 4; ni++) {
            int col = n0 + wc * 64 + ni * 16 + (lane & 15);
            #pragma unroll
            for (int r = 0; r < 4; r++) {
                int rowg = m0 + wr * 64 + mi * 16 + (lane >> 4) * 4 + r;
                size_t off = (size_t)rowg * ldc + col;
                float v = acc[mi][ni][r];
                if constexpr (EPI == 1) {
                    Cf[off] = v + bias[col];
                } else {
                    Pb[off] = f2bf(v);
                }
            }
        }
    }
}

// ---------------------------------------------------------------------------
// topk + build M — r11 structure verbatim (best measured: 133us, VGPR 64,
// no spill): 512-thread blocks = 8 waves = 2 independent rows, 4 waves/row,
// lane owns 16 cols, one barrier per hop (3 total).
// Eleven structural variants (r3-r13: 2/4/8-wave, forced-occ, pipelined,
// streaming, fused-ILP, reg-resident, setprio) all land 128-170us — this
// access pattern's latency/serialization equilibrium. Locked at r11's best.
// Spill tripwire: WRITE_SIZE must stay 32768 KB (r4/r12 lessons).
__global__ __launch_bounds__(512) void topk_build_M(
    const ushort* __restrict__ simb, const float* __restrict__ adj,
    const float* __restrict__ rmask, const float* __restrict__ coef,
    ushort* __restrict__ Mout) {
    const int tid = threadIdx.x;
    const int lane = tid & 63;
    const int w = tid >> 6;
    const int rloc = w >> 2;
    const int wv = w & 3;
    const int row = blockIdx.x * 2 + rloc;
    __shared__ float wl[2][3][4][8];

    const int cbase = wv * 1024 + lane * 4;
    const size_t hopstride = (size_t)NROW * NROW;

    const ushort* srow = simb + (size_t)row * NROW + cbase;
    const float* arow = adj + (size_t)row * NROW + cbase;
    const float* rrow = rmask + (size_t)row * NROW + cbase;

    uint2 svp[4];
    #pragma unroll
    for (int q = 0; q < 4; q++)
        svp[q] = *(const uint2*)(srow + q * 256);

    float macc[4][4];
    #pragma unroll
    for (int q = 0; q < 4; q++)
        #pragma unroll
        for (int c = 0; c < 4; c++) macc[q][c] = 0.f;

    #pragma unroll 1
    for (int k = 0; k < 3; ++k) {
        const float* ar = arow + (size_t)k * hopstride;
        const float* rr = rrow + (size_t)k * hopstride;

        f4 rv[4], a[4];
        #pragma unroll
        for (int q = 0; q < 4; q++) rv[q] = *(const f4*)(rr + q * 256);
        #pragma unroll
        for (int q = 0; q < 4; q++) a[q] = *(const f4*)(ar + q * 256);

        uint32_t rbits = 0;
        #pragma unroll
        for (int q = 0; q < 4; q++) {
            rbits |= (rv[q].x < 0.5f ? 1u : 0u) << (q * 4 + 0);
            rbits |= (rv[q].y < 0.5f ? 1u : 0u) << (q * 4 + 1);
            rbits |= (rv[q].z < 0.5f ? 1u : 0u) << (q * 4 + 2);
            rbits |= (rv[q].w < 0.5f ? 1u : 0u) << (q * 4 + 3);
        }

        uint2 avp[4];
        #pragma unroll
        for (int q = 0; q < 4; q++) {
            avp[q].x = cvt_pk_bf16(a[q].x, a[q].y);
            avp[q].y = cvt_pk_bf16(a[q].z, a[q].w);
        }

        float lo8[8], hi8[8];
        #pragma unroll
        for (int qq = 0; qq < 2; qq++) {
            lo8[qq * 4 + 0] = up0(avp[qq].x) * up0(svp[qq].x);
            lo8[qq * 4 + 1] = up1(avp[qq].x) * up1(svp[qq].x);
            lo8[qq * 4 + 2] = up0(avp[qq].y) * up0(svp[qq].y);
            lo8[qq * 4 + 3] = up1(avp[qq].y) * up1(svp[qq].y);
        }
        #pragma unroll
        for (int qq = 0; qq < 2; qq++) {
            const int q = 2 + qq;
            hi8[qq * 4 + 0] = up0(avp[q].x) * up0(svp[q].x);
            hi8[qq * 4 + 1] = up1(avp[q].x) * up1(svp[q].x);
            hi8[qq * 4 + 2] = up0(avp[q].y) * up0(svp[q].y);
            hi8[qq * 4 + 3] = up1(avp[q].y) * up1(svp[q].y);
        }
        sort8(lo8);
        sort8(hi8);
        mergeTop8(lo8, hi8);

        // wave top-8: 6-level merge tree
        #pragma unroll
        for (int lvl = 0; lvl < 6; lvl++) {
            float b[8];
            #pragma unroll
            for (int i = 0; i < 8; i++) b[i] = __shfl_xor(lo8[i], 1 << lvl);
            mergeTop8(lo8, b);
        }

        if (lane < 8) wl[rloc][k][wv][lane] = lo8[lane];
        __syncthreads();
        float b0[8], b1[8], b2[8];
        const int o0 = (wv + 1) & 3, o1 = (wv + 2) & 3, o2 = (wv + 3) & 3;
        #pragma unroll
        for (int i = 0; i < 8; i++) b0[i] = wl[rloc][k][o0][i];
        #pragma unroll
        for (int i = 0; i < 8; i++) b1[i] = wl[rloc][k][o1][i];
        #pragma unroll
        for (int i = 0; i < 8; i++) b2[i] = wl[rloc][k][o2][i];
        mergeTop8(lo8, b0);
        mergeTop8(lo8, b1);
        const float thr = merge8th(lo8, b2);

        const float ak = coef[k];
        const float aksq = ak * ak;
        #pragma unroll
        for (int q = 0; q < 4; q++) {
            float av0 = up0(avp[q].x), av1 = up1(avp[q].x);
            float av2 = up0(avp[q].y), av3 = up1(avp[q].y);
            float s0 = up0(svp[q].x), s1 = up1(svp[q].x);
            float s2 = up0(svp[q].y), s3 = up1(svp[q].y);
            bool m0 = ((rbits >> (q * 4 + 0)) & 1) || (av0 * s0 >= thr);
            bool m1 = ((rbits >> (q * 4 + 1)) & 1) || (av1 * s1 >= thr);
            bool m2 = ((rbits >> (q * 4 + 2)) & 1) || (av2 * s2 >= thr);
            bool m3 = ((rbits >> (q * 4 + 3)) & 1) || (av3 * s3 >= thr);
            macc[q][0] += m0 ? aksq * av0 : 0.f;
            macc[q][1] += m1 ? aksq * av1 : 0.f;
            macc[q][2] += m2 ? aksq * av2 : 0.f;
            macc[q][3] += m3 ? aksq * av3 : 0.f;
        }
        // no end-of-loop barrier — wl[.][k+1][.] never aliases wl[.][k][.]
    }

    ushort* mrow = Mout + (size_t)row * NROW + cbase;
    #pragma unroll
    for (int q = 0; q < 4; q++) {
        u16x4 o;
        o[0] = f2bf(up0(svp[q].x) * macc[q][0]);
        o[1] = f2bf(up1(svp[q].x) * macc[q][1]);
        o[2] = f2bf(up0(svp[q].y) * macc[q][2]);
        o[3] = f2bf(up1(svp[q].y) * macc[q][3]);
        *(u16x4*)(mrow + q * 256) = o;
    }
}

// ---------------------------------------------------------------------------
// H = relu(cb*(parts4 + bias) + (1-cb)*sum_{z<4} parts[z]) -> bf16
__global__ __launch_bounds__(256) void reduce_relu(
    const ushort* __restrict__ parts, const ushort* __restrict__ parts4,
    const float* __restrict__ bias, const float* __restrict__ coef,
    ushort* __restrict__ Hb) {
    const size_t i = (size_t)blockIdx.x * 256 + threadIdx.x;  // u16x4 index
    f4 s = {0.f, 0.f, 0.f, 0.f};
    #pragma unroll
    for (int z = 0; z < 4; z++) {
        u16x4 p = *((const u16x4*)parts + (size_t)z * 524288 + i);
        #pragma unroll
        for (int c = 0; c < 4; c++) s[c] += bf2f(p[c]);
    }
    u16x4 h4 = *((const u16x4*)parts4 + i);
    f4 bi = ((const f4*)bias)[i & 127];
    float cb = coef[3];
    u16x4 o;
    #pragma unroll
    for (int c = 0; c < 4; c++) {
        float h = cb * (bf2f(h4[c]) + bi[c]) + (1.f - cb) * s[c];
        o[c] = f2bf(fmaxf(h, 0.f));
    }
    *((u16x4*)Hb + i) = o;
}

// ---------------------------------------------------------------------------
__global__ __launch_bounds__(256) void logsoftmax_k(const float* __restrict__ L,
                                                    float* __restrict__ out) {
    int row = blockIdx.x, tid = threadIdx.x;
    int lane = tid & 63, w = tid >> 6;
    const float* lr = L + (size_t)row * 512;
    float v0 = lr[tid], v1 = lr[tid + 256];
    __shared__ float bm[4], bs[4];
    float m = fmaxf(v0, v1);
    m = waveReduceMax(m);
    if (lane == 0) bm[w] = m;
    __syncthreads();
    float M = fmaxf(fmaxf(bm[0], bm[1]), fmaxf(bm[2], bm[3]));
    float s = expf(v0 - M) + expf(v1 - M);
    s = waveReduceSum(s);
    if (lane == 0) bs[w] = s;
    __syncthreads();
    float S = bs[0] + bs[1] + bs[2] + bs[3];
    float lse = M + logf(S);
    float* orow = out + (size_t)row * 512;
    orow[tid] = v0 - lse;
    orow[tid + 256] = v1 - lse;
}

// ---------------------------------------------------------------------------
extern "C" void kernel_launch(void* const* d_in, const int* in_sizes, int n_in,
                              void* d_out, int out_size, void* d_ws, size_t ws_size,
                              hipStream_t stream) {
    const float* x     = (const float*)d_in[0];
    const float* adj   = (const float*)d_in[1];
    const float* rmask = (const float*)d_in[2];
    const float* W_in  = (const float*)d_in[3];
    const float* b_in  = (const float*)d_in[4];
    const float* W_out = (const float*)d_in[5];
    const float* b_out = (const float*)d_in[6];
    const float* alpha = (const float*)d_in[7];
    const float* beta  = (const float*)d_in[8];
    float* out = (float*)d_out;

    const size_t MB = 1024 * 1024;
    char* wsb = (char*)d_ws;
    // [0,32):  simb bf16 (dead after topk) -> parts bf16 4x4MB [0,16)
    //          + parts4 bf16 [16,20) + logits fp32 [20,28)
    // [32,64): Mb bf16
    // [64,68): xn bf16    [68,72): xb bf16    [72,76): xbT bf16
    // [76,76.5): WinT     [76.5,77): WoutT
    // [85,89): Hb bf16    [89): coef
    ushort* simb   = (ushort*)wsb;
    ushort* parts  = (ushort*)wsb;
    ushort* parts4 = (ushort*)(wsb + 16 * MB);
    float*  logits = (float*)(wsb + 20 * MB);
    ushort* Mb     = (ushort*)(wsb + 32 * MB);
    ushort* xn     = (ushort*)(wsb + 64 * MB);
    ushort* xb     = (ushort*)(wsb + 68 * MB);
    ushort* xbT    = (ushort*)(wsb + 72 * MB);
    ushort* WinT   = (ushort*)(wsb + 76 * MB);
    ushort* WoutT  = (ushort*)(wsb + 76 * MB + 512 * 1024);
    ushort* Hb     = (ushort*)(wsb + 85 * MB);
    float*  coef   = (float*)(wsb + 89 * MB);

    // fused prep: xn/xb + x^T + weight transposes + coef (all independent)
    prep_fused<<<4096 + 512 + 128 + 1, 256, 0, stream>>>(
        x, xn, xb, xbT, W_in, WinT, W_out, WoutT, alpha, beta, coef);

    // sim = xn @ xn^T -> bf16 (symmetric: 528 upper-triangle tiles)
    gemm_sym<<<528, 256, 0, stream>>>(xn, simb);

    // combined masked adjacency M (bf16) — 512-thread blocks, 2 rows each
    topk_build_M<<<NROW / 2, 512, 0, stream>>>(simb, adj, rmask, coef, Mb);

    // split-K=4 M@x (z<4, K=1024 each) + H_low (z=4) in ONE dispatch
    gemm_abT<3><<<dim3(4, 32, 5), 256, 0, stream>>>(
        Mb, NROW, xbT, NROW, 1024, 512, nullptr, parts, nullptr,
        xb, WinT, parts4);

    // H = relu(b*(H_low+bias) + (1-b)*sum parts) -> bf16
    reduce_relu<<<2048, 256, 0, stream>>>(parts, parts4, b_in, coef, Hb);

    // logits = H @ W_out + b_out
    gemm_abT<1><<<dim3(4, 32), 256, 0, stream>>>(
        Hb, 512, WoutT, 512, 512, 512, logits, nullptr, b_out,
        nullptr, nullptr, nullptr);

    logsoftmax_k<<<NROW, 256, 0, stream>>>(logits, out);
}

// Round 15
// 190.242 us; speedup vs baseline: 1.3109x; 1.0574x over previous
//
#include <hip/hip_runtime.h>
#include <hip/hip_bf16.h>
#include <stdint.h>

#define NROW 4096
#define FDIM 512

typedef short bf16x8 __attribute__((ext_vector_type(8)));
typedef float f32x4 __attribute__((ext_vector_type(4)));
typedef float f4 __attribute__((ext_vector_type(4)));
typedef ushort u16x4 __attribute__((ext_vector_type(4)));

#define NEG_INF (-__builtin_inff())

__device__ inline ushort f2bf(float f) {
    union { float f; uint32_t u; } c{f};
    uint32_t u = c.u;
    uint32_t r = (u + 0x7FFF + ((u >> 16) & 1)) >> 16;
    return (ushort)r;
}
__device__ inline float bf2f(ushort h) {
    union { uint32_t u; float f; } c{((uint32_t)h) << 16};
    return c.f;
}
// packed bf16 pair helpers: lo = element 0, hi = element 1
__device__ inline uint32_t cvt_pk_bf16(float lo, float hi) {
    uint32_t r;
    asm("v_cvt_pk_bf16_f32 %0, %1, %2" : "=v"(r) : "v"(lo), "v"(hi));
    return r;
}
__device__ inline float up0(uint32_t p) {
    union { uint32_t u; float f; } c{p << 16}; return c.f;
}
__device__ inline float up1(uint32_t p) {
    union { uint32_t u; float f; } c{p & 0xFFFF0000u}; return c.f;
}

__device__ inline float waveReduceMax(float v) {
    #pragma unroll
    for (int o = 32; o > 0; o >>= 1) v = fmaxf(v, __shfl_xor(v, o));
    return v;
}
__device__ inline float waveReduceSum(float v) {
    #pragma unroll
    for (int o = 32; o > 0; o >>= 1) v += __shfl_xor(v, o);
    return v;
}

// ---- sorting-network primitives (descending) -------------------------------
__device__ inline void CE(float& a, float& b) {
    float mx = fmaxf(a, b);
    b = fminf(a, b);
    a = mx;
}
// Batcher odd-even mergesort, 8 elements, descending, 19 comparators
__device__ inline void sort8(float (&l)[8]) {
    CE(l[0],l[1]); CE(l[2],l[3]); CE(l[4],l[5]); CE(l[6],l[7]);
    CE(l[0],l[2]); CE(l[1],l[3]); CE(l[4],l[6]); CE(l[5],l[7]);
    CE(l[1],l[2]); CE(l[5],l[6]);
    CE(l[0],l[4]); CE(l[1],l[5]); CE(l[2],l[6]); CE(l[3],l[7]);
    CE(l[2],l[4]); CE(l[3],l[5]);
    CE(l[1],l[2]); CE(l[3],l[4]); CE(l[5],l[6]);
}
// a, b sorted desc -> a = sorted desc top-8 of union (bitonic half-merge)
__device__ inline void mergeTop8(float (&a)[8], const float (&b)[8]) {
    float t[8];
    #pragma unroll
    for (int i = 0; i < 8; i++) t[i] = fmaxf(a[i], b[7 - i]);
    CE(t[0],t[4]); CE(t[1],t[5]); CE(t[2],t[6]); CE(t[3],t[7]);
    CE(t[0],t[2]); CE(t[1],t[3]); CE(t[4],t[6]); CE(t[5],t[7]);
    CE(t[0],t[1]); CE(t[2],t[3]); CE(t[4],t[5]); CE(t[6],t[7]);
    #pragma unroll
    for (int i = 0; i < 8; i++) a[i] = t[i];
}
// 8th-largest of union of two sorted-8 lists: min of the bitonic half-merge
__device__ inline float merge8th(const float (&a)[8], const float (&b)[8]) {
    float t0 = fminf(fmaxf(a[0], b[7]), fmaxf(a[1], b[6]));
    float t1 = fminf(fmaxf(a[2], b[5]), fmaxf(a[3], b[4]));
    float t2 = fminf(fmaxf(a[4], b[3]), fmaxf(a[5], b[2]));
    float t3 = fminf(fmaxf(a[6], b[1]), fmaxf(a[7], b[0]));
    return fminf(fminf(t0, t1), fminf(t2, t3));
}

#define GLL16(src, dst)                                                        \
    __builtin_amdgcn_global_load_lds(                                          \
        (const __attribute__((address_space(1))) void*)(src),                  \
        (__attribute__((address_space(3))) void*)(dst), 16, 0, 0)

// ---------------------------------------------------------------------------
// Fused preparation: all roles independent (transpose reads x directly).
// blocks [0,4096):    prep_x — row normalize -> xn bf16; cast -> xb bf16
// blocks [4096,4608): transpose x (fp32) -> xbT bf16 (512x4096)
// blocks [4608,4736): conv+transpose W_in / W_out -> WinT / WoutT
// block  4736:        coef = softmax(alpha), beta
__global__ __launch_bounds__(256) void prep_fused(
    const float* __restrict__ x, ushort* __restrict__ xn,
    ushort* __restrict__ xb, ushort* __restrict__ xbT,
    const float* __restrict__ W_in, ushort* __restrict__ WinT,
    const float* __restrict__ W_out, ushort* __restrict__ WoutT,
    const float* __restrict__ alpha, const float* __restrict__ beta,
    float* __restrict__ coef) {
    const int b = blockIdx.x;
    const int tid = threadIdx.x;
    __shared__ float b4[4];
    __shared__ ushort t[64][65];

    if (b >= 4736) {
        if (tid == 0) {
            float a0 = alpha[0], a1 = alpha[1], a2 = alpha[2];
            float m = fmaxf(a0, fmaxf(a1, a2));
            float e0 = expf(a0 - m), e1 = expf(a1 - m), e2 = expf(a2 - m);
            float s = e0 + e1 + e2;
            coef[0] = e0 / s; coef[1] = e1 / s; coef[2] = e2 / s;
            coef[3] = beta[0];
        }
    } else if (b < 4096) {
        const int row = b;
        int lane = tid & 63, w = tid >> 6;
        const float* xr = x + (size_t)row * FDIM;
        float v0 = xr[tid], v1 = xr[tid + 256];
        float ss = v0 * v0 + v1 * v1;
        ss = waveReduceSum(ss);
        if (lane == 0) b4[w] = ss;
        __syncthreads();
        float tot = b4[0] + b4[1] + b4[2] + b4[3];
        float inv = 1.f / fmaxf(sqrtf(tot), 1e-12f);
        size_t o = (size_t)row * FDIM + tid;
        xn[o] = f2bf(v0 * inv);  xn[o + 256] = f2bf(v1 * inv);
        xb[o] = f2bf(v0);        xb[o + 256] = f2bf(v1);
    } else if (b < 4608) {
        const int tb = b - 4096;
        const int c0 = (tb & 7) * 64, r0 = (tb >> 3) * 64;
        int lx = tid & 63, ly = tid >> 6;
        #pragma unroll
        for (int i = 0; i < 16; i++)
            t[ly + 4 * i][lx] = f2bf(x[(size_t)(r0 + ly + 4 * i) * FDIM + c0 + lx]);
        __syncthreads();
        #pragma unroll
        for (int i = 0; i < 16; i++)
            xbT[(size_t)(c0 + ly + 4 * i) * NROW + r0 + lx] = t[lx][ly + 4 * i];
    } else {
        const int cb = b - 4608;
        const float* Wf = (cb >> 6) ? W_out : W_in;
        ushort* WT = (cb >> 6) ? WoutT : WinT;
        const int idx = cb & 63;
        const int c0 = (idx & 7) * 64, r0 = (idx >> 3) * 64;
        int lx = tid & 63, ly = tid >> 6;
        #pragma unroll
        for (int i = 0; i < 16; i++)
            t[ly + 4 * i][lx] = f2bf(Wf[(size_t)(r0 + ly + 4 * i) * 512 + c0 + lx]);
        __syncthreads();
        #pragma unroll
        for (int i = 0; i < 16; i++)
            WT[(size_t)(c0 + ly + 4 * i) * 512 + r0 + lx] = t[lx][ly + 4 * i];
    }
}

// ---------------------------------------------------------------------------
// gemm_sym_hlow: heterogeneous dispatch (656 blocks).
// blocks [0,528):   SYMMETRIC sim GEMM simb = xn @ xn^T (bf16 out), 528
//                   upper-triangle 128x128 tiles; off-diagonal tiles written
//                   twice (normal + LDS-staged transposed).
// blocks [528,656): H_low = xb @ WinT^T -> parts4 bf16 (128 tiles, K=512).
//                   r15: moved here from the split-K dispatch's z=4 tail —
//                   fills gemm_sym's block-quantization tail; split-K drops
//                   to exactly 512 blocks (2.0/CU, no tail).
__global__ __launch_bounds__(256) void gemm_sym_hlow(
    const ushort* __restrict__ A, ushort* __restrict__ C,
    const ushort* __restrict__ xb, const ushort* __restrict__ WinT,
    ushort* __restrict__ parts4) {
    constexpr int BK = 64;
    constexpr int NT = 128 * BK;
    __shared__ __align__(16) ushort smem[128 * 130];  // 33.3KB, both paths
    ushort* As = smem;
    ushort* Bs = smem + NT;

    const int tid = threadIdx.x;
    const int lane = tid & 63, w = tid >> 6;
    const int wr = w >> 1, wc = w & 1;

    f32x4 acc[4][4];
    #pragma unroll
    for (int mi = 0; mi < 4; mi++)
        #pragma unroll
        for (int ni = 0; ni < 4; ni++)
            #pragma unroll
            for (int r = 0; r < 4; r++) acc[mi][ni][r] = 0.f;

    if (blockIdx.x >= 528) {
        // ---- H_low path ----------------------------------------------------
        const int sub = blockIdx.x - 528;
        const int m0 = (sub >> 2) * 128;
        const int n0 = (sub & 3) * 128;
        for (int k0 = 0; k0 < FDIM; k0 += BK) {
            #pragma unroll
            for (int p = 0; p < 4; ++p) {
                int chunk = p * 256 + tid;
                int row = chunk / 8;
                int kc = chunk % 8;
                GLL16(xb + (size_t)(m0 + row) * FDIM + k0 + kc * 8,
                      As + (size_t)(p * 256 + w * 64) * 8);
                GLL16(WinT + (size_t)(n0 + row) * FDIM + k0 + kc * 8,
                      Bs + (size_t)(p * 256 + w * 64) * 8);
            }
            __syncthreads();
            #pragma unroll
            for (int kf = 0; kf < BK / 32; ++kf) {
                const int ko = kf * 32 + (lane >> 4) * 8;
                bf16x8 av[4], bv[4];
                #pragma unroll
                for (int mi = 0; mi < 4; mi++)
                    av[mi] = *(const bf16x8*)&As[(wr * 64 + mi * 16 + (lane & 15)) * BK + ko];
                #pragma unroll
                for (int ni = 0; ni < 4; ni++)
                    bv[ni] = *(const bf16x8*)&Bs[(wc * 64 + ni * 16 + (lane & 15)) * BK + ko];
                #pragma unroll
                for (int mi = 0; mi < 4; mi++)
                    #pragma unroll
                    for (int ni = 0; ni < 4; ni++)
                        acc[mi][ni] = __builtin_amdgcn_mfma_f32_16x16x32_bf16(
                            av[mi], bv[ni], acc[mi][ni], 0, 0, 0);
            }
            __syncthreads();
        }
        #pragma unroll
        for (int mi = 0; mi < 4; mi++) {
            #pragma unroll
            for (int ni = 0; ni < 4; ni++) {
                int col = n0 + wc * 64 + ni * 16 + (lane & 15);
                #pragma unroll
                for (int r = 0; r < 4; r++) {
                    int rowg = m0 + wr * 64 + mi * 16 + (lane >> 4) * 4 + r;
                    parts4[(size_t)rowg * 512 + col] = f2bf(acc[mi][ni][r]);
                }
            }
        }
        return;
    }

    // ---- symmetric sim path ------------------------------------------------
    int bi = 0, rem = blockIdx.x;
    while (rem >= 32 - bi) { rem -= 32 - bi; bi++; }
    const int bj = bi + rem;
    const int m0 = bi * 128, n0 = bj * 128;

    for (int k0 = 0; k0 < FDIM; k0 += BK) {
        #pragma unroll
        for (int p = 0; p < 4; ++p) {
            int chunk = p * 256 + tid;
            int row = chunk / 8;
            int kc = chunk % 8;
            GLL16(A + (size_t)(m0 + row) * FDIM + k0 + kc * 8,
                  As + (size_t)(p * 256 + w * 64) * 8);
            GLL16(A + (size_t)(n0 + row) * FDIM + k0 + kc * 8,
                  Bs + (size_t)(p * 256 + w * 64) * 8);
        }
        __syncthreads();
        #pragma unroll
        for (int kf = 0; kf < BK / 32; ++kf) {
            const int ko = kf * 32 + (lane >> 4) * 8;
            bf16x8 av[4], bv[4];
            #pragma unroll
            for (int mi = 0; mi < 4; mi++)
                av[mi] = *(const bf16x8*)&As[(wr * 64 + mi * 16 + (lane & 15)) * BK + ko];
            #pragma unroll
            for (int ni = 0; ni < 4; ni++)
                bv[ni] = *(const bf16x8*)&Bs[(wc * 64 + ni * 16 + (lane & 15)) * BK + ko];
            #pragma unroll
            for (int mi = 0; mi < 4; mi++)
                #pragma unroll
                for (int ni = 0; ni < 4; ni++)
                    acc[mi][ni] = __builtin_amdgcn_mfma_f32_16x16x32_bf16(
                        av[mi], bv[ni], acc[mi][ni], 0, 0, 0);
        }
        __syncthreads();
    }

    #pragma unroll
    for (int mi = 0; mi < 4; mi++) {
        #pragma unroll
        for (int ni = 0; ni < 4; ni++) {
            int lcol = wc * 64 + ni * 16 + (lane & 15);
            #pragma unroll
            for (int r = 0; r < 4; r++) {
                int lrow = wr * 64 + mi * 16 + (lane >> 4) * 4 + r;
                ushort hv = f2bf(acc[mi][ni][r]);
                C[(size_t)(m0 + lrow) * NROW + n0 + lcol] = hv;
                smem[lrow * 130 + lcol] = hv;
            }
        }
    }

    if (bi != bj) {
        __syncthreads();
        const int wv = w;
        #pragma unroll 4
        for (int i = 0; i < 32; i++) {
            int r2 = wv * 32 + i;
            ushort a = smem[(lane * 2) * 130 + r2];
            ushort bb = smem[(lane * 2 + 1) * 130 + r2];
            uint32_t pk = (uint32_t)a | ((uint32_t)bb << 16);
            *(uint32_t*)&C[(size_t)(n0 + r2) * NROW + m0 + lane * 2] = pk;
        }
    }
}

// ---------------------------------------------------------------------------
// C = A(MxK) * B(NxK)^T, bf16 MFMA 16x16x32, 128x128 tile, 4 waves, BK=64.
// EPI 1: fp32 C + bias[col].
// EPI 3: split-K partials -> BF16, z<4: K-chunk 1024 of M@x into Pb[z].
template <int EPI>
__global__ __launch_bounds__(256) void gemm_abT(
    const ushort* __restrict__ A, int lda,
    const ushort* __restrict__ B, int ldb,
    int Kdim, int ldc,
    float* __restrict__ Cf, ushort* __restrict__ Pb,
    const float* __restrict__ bias) {
    constexpr int BK = 64;
    constexpr int NT = 128 * BK;
    constexpr int CPR = BK / 8;
    constexpr int PASSES = (128 * CPR) / 256;
    __shared__ __align__(16) ushort smem[2 * NT];
    ushort* As = smem;
    ushort* Bs = smem + NT;

    if constexpr (EPI == 3) {
        A += (size_t)blockIdx.z * 1024;
        B += (size_t)blockIdx.z * 1024;
        Pb += (size_t)blockIdx.z * ((size_t)NROW * 512);
    }

    const int tid = threadIdx.x;
    const int lane = tid & 63, w = tid >> 6;
    const int wr = w >> 1, wc = w & 1;
    const int m0 = blockIdx.y * 128;
    const int n0 = blockIdx.x * 128;

    f32x4 acc[4][4];
    #pragma unroll
    for (int mi = 0; mi < 4; mi++)
        #pragma unroll
        for (int ni = 0; ni < 4; ni++)
            #pragma unroll
            for (int r = 0; r < 4; r++) acc[mi][ni][r] = 0.f;

    for (int k0 = 0; k0 < Kdim; k0 += BK) {
        #pragma unroll
        for (int p = 0; p < PASSES; ++p) {
            int chunk = p * 256 + tid;
            int row = chunk / CPR;
            int kc = chunk % CPR;
            const ushort* asrc = A + (size_t)(m0 + row) * lda + k0 + kc * 8;
            const ushort* bsrc = B + (size_t)(n0 + row) * ldb + k0 + kc * 8;
            ushort* abase = As + (size_t)(p * 256 + w * 64) * 8;
            ushort* bbase = Bs + (size_t)(p * 256 + w * 64) * 8;
            GLL16(asrc, abase);
            GLL16(bsrc, bbase);
        }
        __syncthreads();
        #pragma unroll
        for (int kf = 0; kf < BK / 32; ++kf) {
            const int ko = kf * 32 + (lane >> 4) * 8;
            bf16x8 av[4], bv[4];
            #pragma unroll
            for (int mi = 0; mi < 4; mi++)
                av[mi] = *(const bf16x8*)&As[(wr * 64 + mi * 16 + (lane & 15)) * BK + ko];
            #pragma unroll
            for (int ni = 0; ni < 4; ni++)
                bv[ni] = *(const bf16x8*)&Bs[(wc * 64 + ni * 16 + (lane & 15)) * BK + ko];
            #pragma unroll
            for (int mi = 0; mi < 4; mi++)
                #pragma unroll
                for (int ni = 0; ni < 4; ni++)
                    acc[mi][ni] = __builtin_amdgcn_mfma_f32_16x16x32_bf16(
                        av[mi], bv[ni], acc[mi][ni], 0, 0, 0);
        }
        __syncthreads();
    }

    #pragma unroll
    for (int mi = 0; mi < 4; mi++) {
        #pragma unroll
        for (int ni = 0; ni < 4; ni++) {
            int col = n0 + wc * 64 + ni * 16 + (lane & 15);
            #pragma unroll
            for (int r = 0; r < 4; r++) {
                int rowg = m0 + wr * 64 + mi * 16 + (lane >> 4) * 4 + r;
                size_t off = (size_t)rowg * ldc + col;
                float v = acc[mi][ni][r];
                if constexpr (EPI == 1) {
                    Cf[off] = v + bias[col];
                } else {
                    Pb[off] = f2bf(v);
                }
            }
        }
    }
}

// ---------------------------------------------------------------------------
// topk + build M — r11 structure verbatim (best measured: ~133us, VGPR 64,
// no spill): 512-thread blocks = 8 waves = 2 independent rows, 4 waves/row,
// lane owns 16 cols, one barrier per hop (3 total).
// Eleven structural variants (r3-r13) all land 128-170us — this access
// pattern's latency/serialization equilibrium. Locked.
// Spill tripwire: WRITE_SIZE must stay 32768 KB (r4/r12 lessons).
__global__ __launch_bounds__(512) void topk_build_M(
    const ushort* __restrict__ simb, const float* __restrict__ adj,
    const float* __restrict__ rmask, const float* __restrict__ coef,
    ushort* __restrict__ Mout) {
    const int tid = threadIdx.x;
    const int lane = tid & 63;
    const int w = tid >> 6;
    const int rloc = w >> 2;
    const int wv = w & 3;
    const int row = blockIdx.x * 2 + rloc;
    __shared__ float wl[2][3][4][8];

    const int cbase = wv * 1024 + lane * 4;
    const size_t hopstride = (size_t)NROW * NROW;

    const ushort* srow = simb + (size_t)row * NROW + cbase;
    const float* arow = adj + (size_t)row * NROW + cbase;
    const float* rrow = rmask + (size_t)row * NROW + cbase;

    uint2 svp[4];
    #pragma unroll
    for (int q = 0; q < 4; q++)
        svp[q] = *(const uint2*)(srow + q * 256);

    float macc[4][4];
    #pragma unroll
    for (int q = 0; q < 4; q++)
        #pragma unroll
        for (int c = 0; c < 4; c++) macc[q][c] = 0.f;

    #pragma unroll 1
    for (int k = 0; k < 3; ++k) {
        const float* ar = arow + (size_t)k * hopstride;
        const float* rr = rrow + (size_t)k * hopstride;

        f4 rv[4], a[4];
        #pragma unroll
        for (int q = 0; q < 4; q++) rv[q] = *(const f4*)(rr + q * 256);
        #pragma unroll
        for (int q = 0; q < 4; q++) a[q] = *(const f4*)(ar + q * 256);

        uint32_t rbits = 0;
        #pragma unroll
        for (int q = 0; q < 4; q++) {
            rbits |= (rv[q].x < 0.5f ? 1u : 0u) << (q * 4 + 0);
            rbits |= (rv[q].y < 0.5f ? 1u : 0u) << (q * 4 + 1);
            rbits |= (rv[q].z < 0.5f ? 1u : 0u) << (q * 4 + 2);
            rbits |= (rv[q].w < 0.5f ? 1u : 0u) << (q * 4 + 3);
        }

        uint2 avp[4];
        #pragma unroll
        for (int q = 0; q < 4; q++) {
            avp[q].x = cvt_pk_bf16(a[q].x, a[q].y);
            avp[q].y = cvt_pk_bf16(a[q].z, a[q].w);
        }

        float lo8[8], hi8[8];
        #pragma unroll
        for (int qq = 0; qq < 2; qq++) {
            lo8[qq * 4 + 0] = up0(avp[qq].x) * up0(svp[qq].x);
            lo8[qq * 4 + 1] = up1(avp[qq].x) * up1(svp[qq].x);
            lo8[qq * 4 + 2] = up0(avp[qq].y) * up0(svp[qq].y);
            lo8[qq * 4 + 3] = up1(avp[qq].y) * up1(svp[qq].y);
        }
        #pragma unroll
        for (int qq = 0; qq < 2; qq++) {
            const int q = 2 + qq;
            hi8[qq * 4 + 0] = up0(avp[q].x) * up0(svp[q].x);
            hi8[qq * 4 + 1] = up1(avp[q].x) * up1(svp[q].x);
            hi8[qq * 4 + 2] = up0(avp[q].y) * up0(svp[q].y);
            hi8[qq * 4 + 3] = up1(avp[q].y) * up1(svp[q].y);
        }
        sort8(lo8);
        sort8(hi8);
        mergeTop8(lo8, hi8);

        // wave top-8: 6-level merge tree
        #pragma unroll
        for (int lvl = 0; lvl < 6; lvl++) {
            float b[8];
            #pragma unroll
            for (int i = 0; i < 8; i++) b[i] = __shfl_xor(lo8[i], 1 << lvl);
            mergeTop8(lo8, b);
        }

        if (lane < 8) wl[rloc][k][wv][lane] = lo8[lane];
        __syncthreads();
        float b0[8], b1[8], b2[8];
        const int o0 = (wv + 1) & 3, o1 = (wv + 2) & 3, o2 = (wv + 3) & 3;
        #pragma unroll
        for (int i = 0; i < 8; i++) b0[i] = wl[rloc][k][o0][i];
        #pragma unroll
        for (int i = 0; i < 8; i++) b1[i] = wl[rloc][k][o1][i];
        #pragma unroll
        for (int i = 0; i < 8; i++) b2[i] = wl[rloc][k][o2][i];
        mergeTop8(lo8, b0);
        mergeTop8(lo8, b1);
        const float thr = merge8th(lo8, b2);

        const float ak = coef[k];
        const float aksq = ak * ak;
        #pragma unroll
        for (int q = 0; q < 4; q++) {
            float av0 = up0(avp[q].x), av1 = up1(avp[q].x);
            float av2 = up0(avp[q].y), av3 = up1(avp[q].y);
            float s0 = up0(svp[q].x), s1 = up1(svp[q].x);
            float s2 = up0(svp[q].y), s3 = up1(svp[q].y);
            bool m0 = ((rbits >> (q * 4 + 0)) & 1) || (av0 * s0 >= thr);
            bool m1 = ((rbits >> (q * 4 + 1)) & 1) || (av1 * s1 >= thr);
            bool m2 = ((rbits >> (q * 4 + 2)) & 1) || (av2 * s2 >= thr);
            bool m3 = ((rbits >> (q * 4 + 3)) & 1) || (av3 * s3 >= thr);
            macc[q][0] += m0 ? aksq * av0 : 0.f;
            macc[q][1] += m1 ? aksq * av1 : 0.f;
            macc[q][2] += m2 ? aksq * av2 : 0.f;
            macc[q][3] += m3 ? aksq * av3 : 0.f;
        }
        // no end-of-loop barrier — wl[.][k+1][.] never aliases wl[.][k][.]
    }

    ushort* mrow = Mout + (size_t)row * NROW + cbase;
    #pragma unroll
    for (int q = 0; q < 4; q++) {
        u16x4 o;
        o[0] = f2bf(up0(svp[q].x) * macc[q][0]);
        o[1] = f2bf(up1(svp[q].x) * macc[q][1]);
        o[2] = f2bf(up0(svp[q].y) * macc[q][2]);
        o[3] = f2bf(up1(svp[q].y) * macc[q][3]);
        *(u16x4*)(mrow + q * 256) = o;
    }
}

// ---------------------------------------------------------------------------
// H = relu(cb*(parts4 + bias) + (1-cb)*sum_{z<4} parts[z]) -> bf16
__global__ __launch_bounds__(256) void reduce_relu(
    const ushort* __restrict__ parts, const ushort* __restrict__ parts4,
    const float* __restrict__ bias, const float* __restrict__ coef,
    ushort* __restrict__ Hb) {
    const size_t i = (size_t)blockIdx.x * 256 + threadIdx.x;  // u16x4 index
    f4 s = {0.f, 0.f, 0.f, 0.f};
    #pragma unroll
    for (int z = 0; z < 4; z++) {
        u16x4 p = *((const u16x4*)parts + (size_t)z * 524288 + i);
        #pragma unroll
        for (int c = 0; c < 4; c++) s[c] += bf2f(p[c]);
    }
    u16x4 h4 = *((const u16x4*)parts4 + i);
    f4 bi = ((const f4*)bias)[i & 127];
    float cb = coef[3];
    u16x4 o;
    #pragma unroll
    for (int c = 0; c < 4; c++) {
        float h = cb * (bf2f(h4[c]) + bi[c]) + (1.f - cb) * s[c];
        o[c] = f2bf(fmaxf(h, 0.f));
    }
    *((u16x4*)Hb + i) = o;
}

// ---------------------------------------------------------------------------
__global__ __launch_bounds__(256) void logsoftmax_k(const float* __restrict__ L,
                                                    float* __restrict__ out) {
    int row = blockIdx.x, tid = threadIdx.x;
    int lane = tid & 63, w = tid >> 6;
    const float* lr = L + (size_t)row * 512;
    float v0 = lr[tid], v1 = lr[tid + 256];
    __shared__ float bm[4], bs[4];
    float m = fmaxf(v0, v1);
    m = waveReduceMax(m);
    if (lane == 0) bm[w] = m;
    __syncthreads();
    float M = fmaxf(fmaxf(bm[0], bm[1]), fmaxf(bm[2], bm[3]));
    float s = expf(v0 - M) + expf(v1 - M);
    s = waveReduceSum(s);
    if (lane == 0) bs[w] = s;
    __syncthreads();
    float S = bs[0] + bs[1] + bs[2] + bs[3];
    float lse = M + logf(S);
    float* orow = out + (size_t)row * 512;
    orow[tid] = v0 - lse;
    orow[tid + 256] = v1 - lse;
}

// ---------------------------------------------------------------------------
extern "C" void kernel_launch(void* const* d_in, const int* in_sizes, int n_in,
                              void* d_out, int out_size, void* d_ws, size_t ws_size,
                              hipStream_t stream) {
    const float* x     = (const float*)d_in[0];
    const float* adj   = (const float*)d_in[1];
    const float* rmask = (const float*)d_in[2];
    const float* W_in  = (const float*)d_in[3];
    const float* b_in  = (const float*)d_in[4];
    const float* W_out = (const float*)d_in[5];
    const float* b_out = (const float*)d_in[6];
    const float* alpha = (const float*)d_in[7];
    const float* beta  = (const float*)d_in[8];
    float* out = (float*)d_out;

    const size_t MB = 1024 * 1024;
    char* wsb = (char*)d_ws;
    // [0,32):  simb bf16 (dead after topk) -> parts bf16 4x4MB [0,16)
    //          + logits fp32 [20,28)
    // [32,64): Mb bf16
    // [64,68): xn bf16    [68,72): xb bf16    [72,76): xbT bf16
    // [76,76.5): WinT     [76.5,77): WoutT
    // [77,81): parts4 bf16 (H_low, written during gemm_sym_hlow — must NOT
    //          alias simb, which is still live through topk)
    // [85,89): Hb bf16    [89): coef
    ushort* simb   = (ushort*)wsb;
    ushort* parts  = (ushort*)wsb;
    float*  logits = (float*)(wsb + 20 * MB);
    ushort* Mb     = (ushort*)(wsb + 32 * MB);
    ushort* xn     = (ushort*)(wsb + 64 * MB);
    ushort* xb     = (ushort*)(wsb + 68 * MB);
    ushort* xbT    = (ushort*)(wsb + 72 * MB);
    ushort* WinT   = (ushort*)(wsb + 76 * MB);
    ushort* WoutT  = (ushort*)(wsb + 76 * MB + 512 * 1024);
    ushort* parts4 = (ushort*)(wsb + 77 * MB);
    ushort* Hb     = (ushort*)(wsb + 85 * MB);
    float*  coef   = (float*)(wsb + 89 * MB);

    // fused prep: xn/xb + x^T + weight transposes + coef (all independent)
    prep_fused<<<4096 + 512 + 128 + 1, 256, 0, stream>>>(
        x, xn, xb, xbT, W_in, WinT, W_out, WoutT, alpha, beta, coef);

    // sim = xn @ xn^T (528 tiles) + H_low = xb @ WinT^T (128 tiles) fused
    gemm_sym_hlow<<<528 + 128, 256, 0, stream>>>(xn, simb, xb, WinT, parts4);

    // combined masked adjacency M (bf16) — 512-thread blocks, 2 rows each
    topk_build_M<<<NROW / 2, 512, 0, stream>>>(simb, adj, rmask, coef, Mb);

    // split-K=4 M@x (z<4, K=1024 each) — exactly 512 blocks, no tail
    gemm_abT<3><<<dim3(4, 32, 4), 256, 0, stream>>>(
        Mb, NROW, xbT, NROW, 1024, 512, nullptr, parts, nullptr);

    // H = relu(b*(H_low+bias) + (1-b)*sum parts) -> bf16
    reduce_relu<<<2048, 256, 0, stream>>>(parts, parts4, b_in, coef, Hb);

    // logits = H @ W_out + b_out
    gemm_abT<1><<<dim3(4, 32), 256, 0, stream>>>(
        Hb, 512, WoutT, 512, 512, 512, logits, nullptr, b_out);

    logsoftmax_k<<<NROW, 256, 0, stream>>>(logits, out);
}